// Round 4
// baseline (358.726 us; speedup 1.0000x reference)
//
#include <hip/hip_runtime.h>
#include <hip/hip_bf16.h>
#include <math.h>

#define N_NODES 50000
#define N_EDGES 800000
#define DIM 128
#define CLS 32
#define NGRAPH 64
#define LN_EPS 1e-5f
#define NBLK 196                         // dst-buckets of 256 nodes
#define ABLK 256                         // phase-A blocks (1 per CU)
#define EPB (N_EDGES / ABLK)             // 3125 edges per phase-A block
#define EB_STRIDE 7168                   // per-bucket ebuf capacity
#define LCAP 8192                        // per-bucket CSR capacity (fixed stride)
#define ROWS1 (N_NODES + 1)              // 50001 (incl zero pad row)
#define CHK 4                            // feature chunks
#define CW 32                            // features per chunk (64 B rows)
#define NPB 16                           // nodes per agg block (16 waves)
#define AGB (N_NODES / NPB)              // 3125 agg blocks per chunk

typedef __attribute__((ext_vector_type(8))) short bf16x8;
typedef __attribute__((ext_vector_type(4))) float f32x4;

static __device__ __forceinline__ int lower_bound_i(const int* a, int n, int key) {
    int lo = 0, hi = n;
    while (lo < hi) { int mid = (lo + hi) >> 1; if (a[mid] < key) lo = mid + 1; else hi = mid; }
    return lo;
}

// accumulate 4 bf16 (one uint2) into 4 f32
static __device__ __forceinline__ void acc4(float* ac, uint2 v) {
    union { unsigned int b; float f; } lo0, hi0, lo1, hi1;
    lo0.b = v.x << 16;
    hi0.b = v.x & 0xffff0000u;
    lo1.b = v.y << 16;
    hi1.b = v.y & 0xffff0000u;
    ac[0] += lo0.f;
    ac[1] += hi0.f;
    ac[2] += lo1.f;
    ac[3] += hi1.f;
}

// ---- fused prep: chunk-major bf16 convert + weight fragment shuffle --------
// Node buffers are chunk-major [CHK][ROWS1][CW]: chunk c holds features
// c*32..c*32+31. This is simultaneously (a) the gather layout -- one chunk
// is a contiguous 3.2 MB slice that fits every XCD's 4 MB L2 -- and (b) the
// MFMA A-fragment layout (fragment ks == chunk ks).
// WTf per layer: [ct(8)][kk(8)][lane(64)][e(8)], lane=(q<<4)|l15,
// row n = ct*16+l15, col k = kk*32+q*8+e (coalesced 1 KB B-fragment loads).

__global__ __launch_bounds__(256) void prep_kernel(
    const float* __restrict__ x, const float* __restrict__ Wself,
    const float* __restrict__ Wmsg, __hip_bfloat16* __restrict__ XbIn,
    __hip_bfloat16* __restrict__ WTf,
    int* __restrict__ ecur, float* __restrict__ gsum,
    __hip_bfloat16* __restrict__ padA, __hip_bfloat16* __restrict__ padB,
    __hip_bfloat16* __restrict__ padC, __hip_bfloat16* __restrict__ padD) {
    int i = blockIdx.x * 256 + threadIdx.x;  // grid covers N_NODES*DIM/2 = 3.2M
    if (i < N_NODES * DIM / 2) {
        float2 v = ((const float2*)x)[i];
        int n = i >> 6, kk = i & 63;          // kk indexes feature pairs
        int c = kk >> 4;
        ((__hip_bfloat162*)XbIn)[((size_t)c * ROWS1 + n) * 16 + (kk & 15)] =
            __float22bfloat162_rn(v);
    }
    if (i < 3 * 32768) {
        int l = i >> 15;
        int rem = i & 32767;
        int ct = rem >> 12;
        int kk = (rem >> 9) & 7;
        int lane = (rem >> 3) & 63;
        int e = rem & 7;
        int q = lane >> 4, l15 = lane & 15;
        int n = ct * 16 + l15;
        int k = kk * 32 + q * 8 + e;
        float v = (k < 128) ? Wself[l * 16384 + k * 128 + n]
                            : Wmsg[l * 16384 + (k - 128) * 128 + n];
        WTf[i] = __float2bfloat16(v);
    }
    if (i < NBLK) ecur[i] = i * EB_STRIDE;
    if (i < NGRAPH * DIM) gsum[i] = 0.f;
    if (i < 4 * CHK * CW) {  // zero pad row (n = N_NODES) in every chunk
        __hip_bfloat16* bufs[4] = {padA, padB, padC, padD};
        int buf = i >> 7, c = (i >> 5) & 3, e = i & 31;
        bufs[buf][((size_t)c * ROWS1 + N_NODES) * CW + e] = __float2bfloat16(0.f);
    }
}

// ---- phase A: bucket edges by dst>>8, line-exclusive reservations ----------

__global__ __launch_bounds__(1024) void bucket_kernel(
    const int* __restrict__ esrc, const int* __restrict__ edst,
    int* __restrict__ ecur, int* __restrict__ ebuf) {
    __shared__ int bc4[4][NBLK];
    __shared__ int bc[NBLK], bres[NBLK], bcnt[NBLK];
    const int t = threadIdx.x;
    const int e0 = blockIdx.x * EPB;
    for (int i = t; i < 4 * NBLK; i += 1024) ((int*)bc4)[i] = 0;
    __syncthreads();
    int dr[4], sr[4];
#pragma unroll
    for (int it = 0; it < 4; it++) {
        int i = t + it * 1024;
        if (i < EPB) { dr[it] = edst[e0 + i]; sr[it] = esrc[e0 + i]; }
        else { dr[it] = -1; sr[it] = 0; }
    }
    const int cpy = (t >> 6) & 3;
#pragma unroll
    for (int it = 0; it < 4; it++)
        if (dr[it] >= 0) atomicAdd(&bc4[cpy][dr[it] >> 8], 1);
    __syncthreads();
    if (t < NBLK) {
        int c = bc4[0][t] + bc4[1][t] + bc4[2][t] + bc4[3][t];
        int r = (c + 7) & ~7;                   // pad to multiple of 8
        int res = atomicAdd(&ecur[t], r);       // one global atomic per (block,bucket)
        bres[t] = res;
        bcnt[t] = c;
        bc[t] = res;
    }
    __syncthreads();
#pragma unroll
    for (int it = 0; it < 4; it++)
        if (dr[it] >= 0) {
            int d = dr[it];
            int pos = atomicAdd(&bc[d >> 8], 1);
            ebuf[pos] = ((d & 255) << 16) | sr[it];  // src < 50000 < 2^16
        }
    __syncthreads();
    if (t < NBLK) {
        int c = bcnt[t], r = (c + 7) & ~7, base = bres[t];
        for (int j = c; j < r; j++) ebuf[base + j] = -1;  // sentinels
    }
}

// ---- phase B (fused): per-bucket hist + scan + CSR build in LDS ------------
// csr stored as ushort (src < 2^16); pad entries point at zero row N_NODES.

__global__ __launch_bounds__(1024) void csr_fused_kernel(
    const int* __restrict__ ebuf, const int* __restrict__ ecur,
    int* __restrict__ counts, int* __restrict__ off,
    unsigned short* __restrict__ csr) {
    __shared__ int ncnt[256];
    __shared__ int ssc[256];
    __shared__ int cur[256];
    __shared__ unsigned short lcsr[LCAP];
    const int b = blockIdx.x, t = threadIdx.x;
    const int used = ecur[b] - b * EB_STRIDE;
    const int* eb = ebuf + b * EB_STRIDE;
    for (int i = t; i < LCAP / 2; i += 1024)
        ((unsigned int*)lcsr)[i] = 0xC350C350u;  // 50000 | 50000<<16
    if (t < 256) ncnt[t] = 0;
    __syncthreads();
    for (int i = t; i < used; i += 1024) {
        int p = eb[i];
        if (p != -1) atomicAdd(&ncnt[p >> 16], 1);
    }
    __syncthreads();
    int myc = 0, mypad = 0;
    const int gi = b * 256 + t;
    if (t < 256) {
        myc = (gi < N_NODES) ? ncnt[t] : 0;
        mypad = (myc + 7) & ~7;
        ssc[t] = mypad;
    }
    __syncthreads();
    for (int o = 1; o < 256; o <<= 1) {
        int v = 0;
        if (t < 256 && t >= o) v = ssc[t - o];
        __syncthreads();
        if (t < 256) ssc[t] += v;
        __syncthreads();
    }
    if (t < 256) {
        int eoff = ssc[t] - mypad;
        cur[t] = eoff;
        if (gi < N_NODES) {
            off[gi] = b * LCAP + eoff;
            counts[gi] = myc;
        }
    }
    __syncthreads();
    for (int i = t; i < used; i += 1024) {
        int p = eb[i];
        if (p != -1) {
            int pos = atomicAdd(&cur[p >> 16], 1);
            lcsr[pos] = (unsigned short)(p & 0xFFFF);
        }
    }
    __syncthreads();
    const int total = ssc[255];                 // multiple of 8
    int4* dst4 = (int4*)(csr + (size_t)b * LCAP);
    const int4* src4 = (const int4*)lcsr;
    for (int i = t; i < (total >> 3); i += 1024) dst4[i] = src4[i];
}

// ---- agg: chunked neighbor sum, Sg[c][n][:] = sum Xg[c][src][:] ------------
// One wave per (node, chunk); 16 waves/block; blockIdx chunk-major so one
// 3.2 MB chunk slice is the live gather working set (L2-resident per XCD).
// Per 16-edge round: 1 ushort-vector csr read + 2 independent uint2 gathers
// per lane (8 lanes x 8 B cover one 64 B row; 8 rows in flight per load).

__global__ __launch_bounds__(1024) void agg_kernel(
    const __hip_bfloat16* __restrict__ Xg, const int* __restrict__ off,
    const int* __restrict__ counts, const unsigned short* __restrict__ csr,
    __hip_bfloat16* __restrict__ Sg) {
    const int chunk = blockIdx.x / AGB;
    const int nb = blockIdx.x - chunk * AGB;
    const int w = threadIdx.x >> 6, lane = threadIdx.x & 63;
    const int n = nb * NPB + w;
    const int l8 = lane & 7, g8 = lane >> 3;
    const __hip_bfloat16* X = Xg + (size_t)chunk * ROWS1 * CW;
    int b = off[n];
    int e = b + ((counts[n] + 7) & ~7);
    float ac[4] = {0.f, 0.f, 0.f, 0.f};
    int base = b;
    for (; base + 16 <= e; base += 16) {
        int idx16 = csr[base + (lane & 15)];
        int s0 = __shfl(idx16, g8, 64);
        int s1 = __shfl(idx16, 8 + g8, 64);
        uint2 v0 = *(const uint2*)(X + (size_t)s0 * CW + l8 * 4);
        uint2 v1 = *(const uint2*)(X + (size_t)s1 * CW + l8 * 4);
        acc4(ac, v0);
        acc4(ac, v1);
    }
    if (base < e) {  // 8-edge tail
        int idx8 = csr[base + l8];
        int s0 = __shfl(idx8, g8, 64);
        uint2 v0 = *(const uint2*)(X + (size_t)s0 * CW + l8 * 4);
        acc4(ac, v0);
    }
    // reduce across the 8 lane-groups (lane bits 3,4,5)
#pragma unroll
    for (int j = 0; j < 4; j++) {
        ac[j] += __shfl_xor(ac[j], 8, 64);
        ac[j] += __shfl_xor(ac[j], 16, 64);
        ac[j] += __shfl_xor(ac[j], 32, 64);
    }
    if (lane < 8) {
        union { uint2 u; __hip_bfloat162 h[2]; } pk;
        pk.h[0] = __float22bfloat162_rn(make_float2(ac[0], ac[1]));
        pk.h[1] = __float22bfloat162_rn(make_float2(ac[2], ac[3]));
        *(uint2*)(Sg + ((size_t)chunk * ROWS1 + n) * CW + lane * 4) = pk.u;
    }
}

// ---- layer: MFMA H = [Xg|Sg] @ WTf^T; +bias+deg*bmsg, ReLU, LN, pool -------
// No LDS, no barriers: A-fragments read chunk-major from global (fragment
// ks == chunk ks), B-fragments fragment-ordered from WTf (L2-resident).

__global__ __launch_bounds__(256) void layer_mfma_kernel(
    const __hip_bfloat16* __restrict__ Xg, const __hip_bfloat16* __restrict__ Sg,
    const __hip_bfloat16* __restrict__ WTf,  // fragment-ordered, this layer
    const float* __restrict__ bself, const float* __restrict__ bmsg,
    const int* __restrict__ counts,
    const float* __restrict__ lng, const float* __restrict__ lnb,
    const int* __restrict__ batch, float* __restrict__ gsum,
    __hip_bfloat16* __restrict__ Xout, int do_ln, int do_pool) {
    const int tid = threadIdx.x;
    const int w = tid >> 6, lane = tid & 63;
    const int l15 = lane & 15, q = lane >> 4;
    const int growbase = blockIdx.x * 64 + w * 16;
    const int row = growbase + l15;
    const int rowc = min(row, N_NODES);  // pad row N_NODES is all zeros

    f32x4 acc[8];
#pragma unroll
    for (int ct = 0; ct < 8; ct++) acc[ct] = (f32x4){0.f, 0.f, 0.f, 0.f};

#pragma unroll
    for (int ks = 0; ks < 4; ks++) {
        bf16x8 afrag = *(const bf16x8*)(Xg + ((size_t)ks * ROWS1 + rowc) * CW + q * 8);
#pragma unroll
        for (int ct = 0; ct < 8; ct++) {
            bf16x8 bfrag = *(const bf16x8*)(WTf + (((ct * 8 + ks) * 64) + lane) * 8);
            acc[ct] = __builtin_amdgcn_mfma_f32_16x16x32_bf16(afrag, bfrag, acc[ct], 0, 0, 0);
        }
    }
#pragma unroll
    for (int ks = 0; ks < 4; ks++) {
        bf16x8 afrag = *(const bf16x8*)(Sg + ((size_t)ks * ROWS1 + rowc) * CW + q * 8);
#pragma unroll
        for (int ct = 0; ct < 8; ct++) {
            bf16x8 bfrag = *(const bf16x8*)(WTf + (((ct * 8 + 4 + ks) * 64) + lane) * 8);
            acc[ct] = __builtin_amdgcn_mfma_f32_16x16x32_bf16(afrag, bfrag, acc[ct], 0, 0, 0);
        }
    }

    // ---- epilogue: lane holds rows (q*4+r), cols (ct*16+l15) ----
    float racc[8];
#pragma unroll
    for (int ct = 0; ct < 8; ct++) racc[ct] = 0.f;
    int gw = 0;
    bool fastp = false;
    if (do_pool) {
        int first = (growbase < N_NODES) ? growbase : (N_NODES - 1);
        gw = batch[first];
        int lastrow = growbase + 15;
        fastp = (growbase < N_NODES) && (lastrow < N_NODES) && (batch[lastrow] == gw);
    }
#pragma unroll
    for (int r = 0; r < 4; r++) {
        int grow = growbase + q * 4 + r;
        bool valid = grow < N_NODES;
        float dg = valid ? (float)counts[grow] : 0.f;
        float v[8];
        float s1 = 0.f;
#pragma unroll
        for (int ct = 0; ct < 8; ct++) {
            int col = ct * 16 + l15;
            float h = acc[ct][r] + bself[col] + dg * bmsg[col];
            h = fmaxf(h, 0.f);
            v[ct] = h;
            s1 += h;
        }
        if (do_ln) {
#pragma unroll
            for (int m = 1; m < 16; m <<= 1) s1 += __shfl_xor(s1, m, 64);
            float mu = s1 * (1.0f / 128.0f);
            float s2 = 0.f;
#pragma unroll
            for (int ct = 0; ct < 8; ct++) { float d = v[ct] - mu; s2 += d * d; }
#pragma unroll
            for (int m = 1; m < 16; m <<= 1) s2 += __shfl_xor(s2, m, 64);
            float rs = rsqrtf(s2 * (1.0f / 128.0f) + LN_EPS);
#pragma unroll
            for (int ct = 0; ct < 8; ct++) {
                int col = ct * 16 + l15;
                v[ct] = lng[col] * (v[ct] - mu) * rs + lnb[col];
            }
        }
        if (do_pool) {
            if (fastp) {
#pragma unroll
                for (int ct = 0; ct < 8; ct++) racc[ct] += v[ct];
            } else if (valid) {
                int g = batch[grow];
#pragma unroll
                for (int ct = 0; ct < 8; ct++)
                    atomicAdd(&gsum[g * DIM + ct * 16 + l15], v[ct]);
            }
        } else if (valid) {
            // chunk-major store: col = ct*16+l15 -> chunk ct>>1, elem (ct&1)*16+l15
#pragma unroll
            for (int ct = 0; ct < 8; ct++)
                Xout[((size_t)(ct >> 1) * ROWS1 + grow) * CW + (ct & 1) * 16 + l15] =
                    __float2bfloat16(v[ct]);
        }
    }
    if (do_pool && fastp) {
#pragma unroll
        for (int ct = 0; ct < 8; ct++) {
            racc[ct] += __shfl_xor(racc[ct], 16, 64);
            racc[ct] += __shfl_xor(racc[ct], 32, 64);
        }
        if (q == 0) {
#pragma unroll
            for (int ct = 0; ct < 8; ct++)
                atomicAdd(&gsum[gw * DIM + ct * 16 + l15], racc[ct]);
        }
    }
}

// ---- head: mean + MLP + log_softmax ----------------------------------------

__global__ __launch_bounds__(128) void head_kernel(
    const float* __restrict__ gsum, const int* __restrict__ batch,
    const float* __restrict__ W1, const float* __restrict__ b1,
    const float* __restrict__ W2, const float* __restrict__ b2,
    float* __restrict__ out) {
    __shared__ float p[128];
    __shared__ float hh[128];
    int g = blockIdx.x;
    int j = threadIdx.x;
    int lo = lower_bound_i(batch, N_NODES, g);
    int hi = lower_bound_i(batch, N_NODES, g + 1);
    float cnt = fmaxf((float)(hi - lo), 1.0f);
    p[j] = gsum[g * DIM + j] / cnt;
    __syncthreads();
    float s = b1[j];
    for (int k = 0; k < DIM; k++) s += p[k] * W1[k * DIM + j];
    hh[j] = s;
    __syncthreads();
    if (j < CLS) {
        float l = b2[j];
        for (int k = 0; k < DIM; k++) l += hh[k] * W2[k * CLS + j];
        float mx = l;
#pragma unroll
        for (int m = 16; m >= 1; m >>= 1) mx = fmaxf(mx, __shfl_xor(mx, m, 64));
        float ex = expf(l - mx);
        float se = ex;
#pragma unroll
        for (int m = 16; m >= 1; m >>= 1) se += __shfl_xor(se, m, 64);
        out[g * CLS + j] = l - mx - logf(se);
    }
}

// ---- launch ----------------------------------------------------------------

extern "C" void kernel_launch(void* const* d_in, const int* in_sizes, int n_in,
                              void* d_out, int out_size, void* d_ws, size_t ws_size,
                              hipStream_t stream) {
    (void)in_sizes; (void)n_in; (void)out_size; (void)ws_size;
    const float* x     = (const float*)d_in[0];
    const float* Wself = (const float*)d_in[1];
    const float* bself = (const float*)d_in[2];
    const float* Wmsg  = (const float*)d_in[3];
    const float* bmsg  = (const float*)d_in[4];
    const float* lng   = (const float*)d_in[5];
    const float* lnb   = (const float*)d_in[6];
    const float* W1    = (const float*)d_in[7];
    const float* b1    = (const float*)d_in[8];
    const float* W2    = (const float*)d_in[9];
    const float* b2    = (const float*)d_in[10];
    const int*   ei    = (const int*)d_in[11];
    const int*   batch = (const int*)d_in[12];
    const int* esrc = ei;
    const int* edst = ei + N_EDGES;

    char* w = (char*)d_ws;
    size_t o = 0;
    auto alloc = [&](size_t bytes) { void* p = w + o; o += (bytes + 255) & ~(size_t)255; return p; };
    const size_t XSZ = (size_t)CHK * ROWS1 * CW * 2;  // 12.8 MB chunk-major
    __hip_bfloat16* XbIn = (__hip_bfloat16*)alloc(XSZ);
    __hip_bfloat16* Xb0  = (__hip_bfloat16*)alloc(XSZ);
    __hip_bfloat16* Xb1  = (__hip_bfloat16*)alloc(XSZ);
    __hip_bfloat16* Sg   = (__hip_bfloat16*)alloc(XSZ);
    __hip_bfloat16* WTf  = (__hip_bfloat16*)alloc((size_t)3 * 32768 * 2);
    int*   counts = (int*)alloc((size_t)N_NODES * 4);
    int*   offs   = (int*)alloc((size_t)(N_NODES + 1) * 4);
    int*   ecur   = (int*)alloc((size_t)NBLK * 4);
    int*   ebuf   = (int*)alloc((size_t)NBLK * EB_STRIDE * 4);
    unsigned short* csr = (unsigned short*)alloc((size_t)NBLK * LCAP * 2);
    float* gsum   = (float*)alloc((size_t)NGRAPH * DIM * 4);

    // fused prep: chunk-major bf16 convert + WTf shuffle + zero scratch/pads
    prep_kernel<<<(N_NODES * DIM / 2 + 255) / 256, 256, 0, stream>>>(
        x, Wself, Wmsg, XbIn, WTf, ecur, gsum, XbIn, Xb0, Xb1, Sg);

    // CSR build: bucket -> fused(hist+scan+build), fixed per-bucket stride
    bucket_kernel<<<ABLK, 1024, 0, stream>>>(esrc, edst, ecur, ebuf);
    csr_fused_kernel<<<NBLK, 1024, 0, stream>>>(ebuf, ecur, counts, offs, csr);

    const __hip_bfloat16* XbCur = XbIn;
    __hip_bfloat16* bbufs[3] = {Xb0, Xb1, Xb0};
    for (int i = 0; i < 3; i++) {
        agg_kernel<<<CHK * AGB, 1024, 0, stream>>>(XbCur, offs, counts, csr, Sg);
        layer_mfma_kernel<<<(N_NODES + 63) / 64, 256, 0, stream>>>(
            XbCur, Sg, WTf + (size_t)i * 32768,
            bself + i * DIM, bmsg + i * DIM, counts,
            (i < 2) ? lng + i * DIM : lng, (i < 2) ? lnb + i * DIM : lnb,
            batch, gsum,
            bbufs[i], (i < 2) ? 1 : 0, (i == 2) ? 1 : 0);
        XbCur = bbufs[i];
    }

    head_kernel<<<NGRAPH, 128, 0, stream>>>(gsum, batch, W1, b1, W2, b2, (float*)d_out);
}

// Round 5
// 329.320 us; speedup vs baseline: 1.0893x; 1.0893x over previous
//
#include <hip/hip_runtime.h>
#include <hip/hip_bf16.h>
#include <math.h>

#define N_NODES 50000
#define N_EDGES 800000
#define DIM 128
#define CLS 32
#define NGRAPH 64
#define LN_EPS 1e-5f
#define NBLK 196                         // dst-buckets of 256 nodes
#define ABLK 256                         // phase-A blocks (1 per CU)
#define EPB (N_EDGES / ABLK)             // 3125 edges per phase-A block
#define EB_STRIDE 7168                   // per-bucket ebuf capacity
#define LCAP 8192                        // per-bucket CSR capacity (fixed stride)
#define ROWS1 (N_NODES + 1)              // 50001 (incl zero pad row)
#define CHK 4                            // feature chunks
#define CW 32                            // features per chunk (64 B rows)
#define NPW 4                            // nodes per agg wave (4 gathers in flight)
#define NPB2 (16 * NPW)                  // 64 nodes per 1024-thread agg block
#define NCB ((N_NODES + NPB2 - 1) / NPB2)  // 782 node-blocks per chunk
#define SLOTH ((NCB + 1) / 2)            // 391 node-blocks per XCD slot

typedef __attribute__((ext_vector_type(8))) short bf16x8;
typedef __attribute__((ext_vector_type(4))) float f32x4;
typedef __attribute__((ext_vector_type(2))) unsigned int u32x2;

static __device__ __forceinline__ int lower_bound_i(const int* a, int n, int key) {
    int lo = 0, hi = n;
    while (lo < hi) { int mid = (lo + hi) >> 1; if (a[mid] < key) lo = mid + 1; else hi = mid; }
    return lo;
}

// accumulate 4 bf16 (one u32x2) into 4 f32
static __device__ __forceinline__ void acc4(float* ac, u32x2 v) {
    union { unsigned int b; float f; } lo0, hi0, lo1, hi1;
    lo0.b = v.x << 16;
    hi0.b = v.x & 0xffff0000u;
    lo1.b = v.y << 16;
    hi1.b = v.y & 0xffff0000u;
    ac[0] += lo0.f;
    ac[1] += hi0.f;
    ac[2] += lo1.f;
    ac[3] += hi1.f;
}

// ---- fused prep: chunk-major bf16 convert + weight fragment shuffle --------
// Node buffers chunk-major [CHK][ROWS1][CW]; chunk c = features c*32..c*32+31.
// XbIn stores nontemporal (consumed cross-XCD; keep L2 clean for gather).

__global__ __launch_bounds__(256) void prep_kernel(
    const float* __restrict__ x, const float* __restrict__ Wself,
    const float* __restrict__ Wmsg, __hip_bfloat16* __restrict__ XbIn,
    __hip_bfloat16* __restrict__ WTf,
    int* __restrict__ ecur, float* __restrict__ gsum,
    __hip_bfloat16* __restrict__ padA, __hip_bfloat16* __restrict__ padB,
    __hip_bfloat16* __restrict__ padC, __hip_bfloat16* __restrict__ padD) {
    int i = blockIdx.x * 256 + threadIdx.x;  // grid covers N_NODES*DIM/2 = 3.2M
    if (i < N_NODES * DIM / 2) {
        float2 v = ((const float2*)x)[i];
        int n = i >> 6, kk = i & 63;          // kk indexes feature pairs
        int c = kk >> 4;
        __hip_bfloat162 hv = __float22bfloat162_rn(v);
        __builtin_nontemporal_store(*(unsigned int*)&hv,
            (unsigned int*)XbIn + ((size_t)c * ROWS1 + n) * 16 + (kk & 15));
    }
    if (i < 3 * 32768) {
        int l = i >> 15;
        int rem = i & 32767;
        int ct = rem >> 12;
        int kk = (rem >> 9) & 7;
        int lane = (rem >> 3) & 63;
        int e = rem & 7;
        int q = lane >> 4, l15 = lane & 15;
        int n = ct * 16 + l15;
        int k = kk * 32 + q * 8 + e;
        float v = (k < 128) ? Wself[l * 16384 + k * 128 + n]
                            : Wmsg[l * 16384 + (k - 128) * 128 + n];
        WTf[i] = __float2bfloat16(v);
    }
    if (i < NBLK) ecur[i] = i * EB_STRIDE;
    if (i < NGRAPH * DIM) gsum[i] = 0.f;
    if (i < 4 * CHK * CW) {  // zero pad row (n = N_NODES) in every chunk
        __hip_bfloat16* bufs[4] = {padA, padB, padC, padD};
        int buf = i >> 7, c = (i >> 5) & 3, e = i & 31;
        bufs[buf][((size_t)c * ROWS1 + N_NODES) * CW + e] = __float2bfloat16(0.f);
    }
}

// ---- phase A: bucket edges by dst>>8, line-exclusive reservations ----------

__global__ __launch_bounds__(1024) void bucket_kernel(
    const int* __restrict__ esrc, const int* __restrict__ edst,
    int* __restrict__ ecur, int* __restrict__ ebuf) {
    __shared__ int bc4[4][NBLK];
    __shared__ int bc[NBLK], bres[NBLK], bcnt[NBLK];
    const int t = threadIdx.x;
    const int e0 = blockIdx.x * EPB;
    for (int i = t; i < 4 * NBLK; i += 1024) ((int*)bc4)[i] = 0;
    __syncthreads();
    int dr[4], sr[4];
#pragma unroll
    for (int it = 0; it < 4; it++) {
        int i = t + it * 1024;
        if (i < EPB) { dr[it] = edst[e0 + i]; sr[it] = esrc[e0 + i]; }
        else { dr[it] = -1; sr[it] = 0; }
    }
    const int cpy = (t >> 6) & 3;
#pragma unroll
    for (int it = 0; it < 4; it++)
        if (dr[it] >= 0) atomicAdd(&bc4[cpy][dr[it] >> 8], 1);
    __syncthreads();
    if (t < NBLK) {
        int c = bc4[0][t] + bc4[1][t] + bc4[2][t] + bc4[3][t];
        int r = (c + 7) & ~7;                   // pad to multiple of 8
        int res = atomicAdd(&ecur[t], r);       // one global atomic per (block,bucket)
        bres[t] = res;
        bcnt[t] = c;
        bc[t] = res;
    }
    __syncthreads();
#pragma unroll
    for (int it = 0; it < 4; it++)
        if (dr[it] >= 0) {
            int d = dr[it];
            int pos = atomicAdd(&bc[d >> 8], 1);
            ebuf[pos] = ((d & 255) << 16) | sr[it];  // src < 50000 < 2^16
        }
    __syncthreads();
    if (t < NBLK) {
        int c = bcnt[t], r = (c + 7) & ~7, base = bres[t];
        for (int j = c; j < r; j++) ebuf[base + j] = -1;  // sentinels
    }
}

// ---- phase B (fused): per-bucket hist + scan + CSR build in LDS ------------
// csr stored as ushort (src < 2^16); pad entries point at zero row N_NODES.

__global__ __launch_bounds__(1024) void csr_fused_kernel(
    const int* __restrict__ ebuf, const int* __restrict__ ecur,
    int* __restrict__ counts, int* __restrict__ off,
    unsigned short* __restrict__ csr) {
    __shared__ int ncnt[256];
    __shared__ int ssc[256];
    __shared__ int cur[256];
    __shared__ unsigned short lcsr[LCAP];
    const int b = blockIdx.x, t = threadIdx.x;
    const int used = ecur[b] - b * EB_STRIDE;
    const int* eb = ebuf + b * EB_STRIDE;
    for (int i = t; i < LCAP / 2; i += 1024)
        ((unsigned int*)lcsr)[i] = 0xC350C350u;  // 50000 | 50000<<16
    if (t < 256) ncnt[t] = 0;
    __syncthreads();
    for (int i = t; i < used; i += 1024) {
        int p = eb[i];
        if (p != -1) atomicAdd(&ncnt[p >> 16], 1);
    }
    __syncthreads();
    int myc = 0, mypad = 0;
    const int gi = b * 256 + t;
    if (t < 256) {
        myc = (gi < N_NODES) ? ncnt[t] : 0;
        mypad = (myc + 7) & ~7;
        ssc[t] = mypad;
    }
    __syncthreads();
    for (int o = 1; o < 256; o <<= 1) {
        int v = 0;
        if (t < 256 && t >= o) v = ssc[t - o];
        __syncthreads();
        if (t < 256) ssc[t] += v;
        __syncthreads();
    }
    if (t < 256) {
        int eoff = ssc[t] - mypad;
        cur[t] = eoff;
        if (gi < N_NODES) {
            off[gi] = b * LCAP + eoff;
            counts[gi] = myc;
        }
    }
    __syncthreads();
    for (int i = t; i < used; i += 1024) {
        int p = eb[i];
        if (p != -1) {
            int pos = atomicAdd(&cur[p >> 16], 1);
            lcsr[pos] = (unsigned short)(p & 0xFFFF);
        }
    }
    __syncthreads();
    const int total = ssc[255];                 // multiple of 8
    int4* dst4 = (int4*)(csr + (size_t)b * LCAP);
    const int4* src4 = (const int4*)lcsr;
    for (int i = t; i < (total >> 3); i += 1024) dst4[i] = src4[i];
}

// ---- agg: chunked neighbor sum with XCD-pinned chunks ----------------------
// Dispatch heuristic: blockIdx % 8 ~ XCD. chunk = slot&3 -> each XCD only
// ever touches ONE 3.2 MB chunk slice (fits its 4 MB L2); the two slots
// sharing a chunk split the node range. Expected FETCH ~33 MB (was 55).
// Each wave owns NPW=4 nodes -> 4 independent gathers in flight per round.
// Sg stores nontemporal (write stream must not evict the resident slice).

__global__ __launch_bounds__(1024) void agg_kernel(
    const __hip_bfloat16* __restrict__ Xg, const int* __restrict__ off,
    const int* __restrict__ counts, const unsigned short* __restrict__ csr,
    __hip_bfloat16* __restrict__ Sg) {
    const int b = blockIdx.x;
    const int slot = b & 7;
    const int chunk = slot & 3;
    const int half = slot >> 2;
    const int nbidx = (b >> 3) * 2 + half;      // [0, NCB)
    const int w = threadIdx.x >> 6, lane = threadIdx.x & 63;
    const int l8 = lane & 7, g8 = lane >> 3;
    const __hip_bfloat16* X = Xg + (size_t)chunk * ROWS1 * CW;
    const int nbase = nbidx * NPB2 + w * NPW;

    int bj[NPW], ej[NPW];
    float ac[NPW][4];
#pragma unroll
    for (int j = 0; j < NPW; j++) {
        int n = nbase + j;
        if (n < N_NODES) { bj[j] = off[n]; ej[j] = bj[j] + ((counts[n] + 7) & ~7); }
        else { bj[j] = 0; ej[j] = 0; }
        ac[j][0] = ac[j][1] = ac[j][2] = ac[j][3] = 0.f;
    }
    // joint rounds: 8 edges per node per round, 4 independent gather chains
    for (;;) {
        bool all8 = true;
#pragma unroll
        for (int j = 0; j < NPW; j++) all8 = all8 && (bj[j] + 8 <= ej[j]);
        if (!all8) break;
        int s[NPW];
#pragma unroll
        for (int j = 0; j < NPW; j++) {
            int idx8 = csr[bj[j] + l8];
            s[j] = __shfl(idx8, g8, 64);
        }
        u32x2 v[NPW];
#pragma unroll
        for (int j = 0; j < NPW; j++)
            v[j] = *(const u32x2*)(X + (size_t)s[j] * CW + l8 * 4);
#pragma unroll
        for (int j = 0; j < NPW; j++) { acc4(ac[j], v[j]); bj[j] += 8; }
    }
    // per-node drains (padded to multiples of 8)
#pragma unroll
    for (int j = 0; j < NPW; j++) {
        while (bj[j] < ej[j]) {
            int idx8 = csr[bj[j] + l8];
            int s0 = __shfl(idx8, g8, 64);
            u32x2 v0 = *(const u32x2*)(X + (size_t)s0 * CW + l8 * 4);
            acc4(ac[j], v0);
            bj[j] += 8;
        }
    }
    // reduce across the 8 lane-groups (lane bits 3,4,5)
#pragma unroll
    for (int j = 0; j < NPW; j++)
#pragma unroll
        for (int k = 0; k < 4; k++) {
            ac[j][k] += __shfl_xor(ac[j][k], 8, 64);
            ac[j][k] += __shfl_xor(ac[j][k], 16, 64);
            ac[j][k] += __shfl_xor(ac[j][k], 32, 64);
        }
    if (lane < 8) {
#pragma unroll
        for (int j = 0; j < NPW; j++) {
            int n = nbase + j;
            if (n < N_NODES) {
                union { u32x2 u; __hip_bfloat162 h[2]; } pk;
                pk.h[0] = __float22bfloat162_rn(make_float2(ac[j][0], ac[j][1]));
                pk.h[1] = __float22bfloat162_rn(make_float2(ac[j][2], ac[j][3]));
                __builtin_nontemporal_store(pk.u,
                    (u32x2*)(Sg + ((size_t)chunk * ROWS1 + n) * CW + lane * 4));
            }
        }
    }
}

// ---- layer: MFMA H = [Xg|Sg] @ WTf^T; +bias+deg*bmsg, ReLU, LN, pool -------
// No LDS, no barriers: A-fragments chunk-major from global (fragment ks ==
// chunk ks), B-fragments fragment-ordered from WTf. Xout stores nontemporal.

__global__ __launch_bounds__(256) void layer_mfma_kernel(
    const __hip_bfloat16* __restrict__ Xg, const __hip_bfloat16* __restrict__ Sg,
    const __hip_bfloat16* __restrict__ WTf,  // fragment-ordered, this layer
    const float* __restrict__ bself, const float* __restrict__ bmsg,
    const int* __restrict__ counts,
    const float* __restrict__ lng, const float* __restrict__ lnb,
    const int* __restrict__ batch, float* __restrict__ gsum,
    __hip_bfloat16* __restrict__ Xout, int do_ln, int do_pool) {
    const int tid = threadIdx.x;
    const int w = tid >> 6, lane = tid & 63;
    const int l15 = lane & 15, q = lane >> 4;
    const int growbase = blockIdx.x * 64 + w * 16;
    const int row = growbase + l15;
    const int rowc = min(row, N_NODES);  // pad row N_NODES is all zeros

    f32x4 acc[8];
#pragma unroll
    for (int ct = 0; ct < 8; ct++) acc[ct] = (f32x4){0.f, 0.f, 0.f, 0.f};

#pragma unroll
    for (int ks = 0; ks < 4; ks++) {
        bf16x8 afrag = *(const bf16x8*)(Xg + ((size_t)ks * ROWS1 + rowc) * CW + q * 8);
#pragma unroll
        for (int ct = 0; ct < 8; ct++) {
            bf16x8 bfrag = *(const bf16x8*)(WTf + (((ct * 8 + ks) * 64) + lane) * 8);
            acc[ct] = __builtin_amdgcn_mfma_f32_16x16x32_bf16(afrag, bfrag, acc[ct], 0, 0, 0);
        }
    }
#pragma unroll
    for (int ks = 0; ks < 4; ks++) {
        bf16x8 afrag = *(const bf16x8*)(Sg + ((size_t)ks * ROWS1 + rowc) * CW + q * 8);
#pragma unroll
        for (int ct = 0; ct < 8; ct++) {
            bf16x8 bfrag = *(const bf16x8*)(WTf + (((ct * 8 + 4 + ks) * 64) + lane) * 8);
            acc[ct] = __builtin_amdgcn_mfma_f32_16x16x32_bf16(afrag, bfrag, acc[ct], 0, 0, 0);
        }
    }

    // ---- epilogue: lane holds rows (q*4+r), cols (ct*16+l15) ----
    float racc[8];
#pragma unroll
    for (int ct = 0; ct < 8; ct++) racc[ct] = 0.f;
    int gw = 0;
    bool fastp = false;
    if (do_pool) {
        int first = (growbase < N_NODES) ? growbase : (N_NODES - 1);
        gw = batch[first];
        int lastrow = growbase + 15;
        fastp = (growbase < N_NODES) && (lastrow < N_NODES) && (batch[lastrow] == gw);
    }
#pragma unroll
    for (int r = 0; r < 4; r++) {
        int grow = growbase + q * 4 + r;
        bool valid = grow < N_NODES;
        float dg = valid ? (float)counts[grow] : 0.f;
        float v[8];
        float s1 = 0.f;
#pragma unroll
        for (int ct = 0; ct < 8; ct++) {
            int col = ct * 16 + l15;
            float h = acc[ct][r] + bself[col] + dg * bmsg[col];
            h = fmaxf(h, 0.f);
            v[ct] = h;
            s1 += h;
        }
        if (do_ln) {
#pragma unroll
            for (int m = 1; m < 16; m <<= 1) s1 += __shfl_xor(s1, m, 64);
            float mu = s1 * (1.0f / 128.0f);
            float s2 = 0.f;
#pragma unroll
            for (int ct = 0; ct < 8; ct++) { float d = v[ct] - mu; s2 += d * d; }
#pragma unroll
            for (int m = 1; m < 16; m <<= 1) s2 += __shfl_xor(s2, m, 64);
            float rs = rsqrtf(s2 * (1.0f / 128.0f) + LN_EPS);
#pragma unroll
            for (int ct = 0; ct < 8; ct++) {
                int col = ct * 16 + l15;
                v[ct] = lng[col] * (v[ct] - mu) * rs + lnb[col];
            }
        }
        if (do_pool) {
            if (fastp) {
#pragma unroll
                for (int ct = 0; ct < 8; ct++) racc[ct] += v[ct];
            } else if (valid) {
                int g = batch[grow];
#pragma unroll
                for (int ct = 0; ct < 8; ct++)
                    atomicAdd(&gsum[g * DIM + ct * 16 + l15], v[ct]);
            }
        } else if (valid) {
            // chunk-major store: col = ct*16+l15 -> chunk ct>>1, elem (ct&1)*16+l15
#pragma unroll
            for (int ct = 0; ct < 8; ct++) {
                __hip_bfloat16 hv = __float2bfloat16(v[ct]);
                __builtin_nontemporal_store(*(unsigned short*)&hv,
                    (unsigned short*)Xout +
                        ((size_t)(ct >> 1) * ROWS1 + grow) * CW + (ct & 1) * 16 + l15);
            }
        }
    }
    if (do_pool && fastp) {
#pragma unroll
        for (int ct = 0; ct < 8; ct++) {
            racc[ct] += __shfl_xor(racc[ct], 16, 64);
            racc[ct] += __shfl_xor(racc[ct], 32, 64);
        }
        if (q == 0) {
#pragma unroll
            for (int ct = 0; ct < 8; ct++)
                atomicAdd(&gsum[gw * DIM + ct * 16 + l15], racc[ct]);
        }
    }
}

// ---- head: mean + MLP + log_softmax ----------------------------------------

__global__ __launch_bounds__(128) void head_kernel(
    const float* __restrict__ gsum, const int* __restrict__ batch,
    const float* __restrict__ W1, const float* __restrict__ b1,
    const float* __restrict__ W2, const float* __restrict__ b2,
    float* __restrict__ out) {
    __shared__ float p[128];
    __shared__ float hh[128];
    int g = blockIdx.x;
    int j = threadIdx.x;
    int lo = lower_bound_i(batch, N_NODES, g);
    int hi = lower_bound_i(batch, N_NODES, g + 1);
    float cnt = fmaxf((float)(hi - lo), 1.0f);
    p[j] = gsum[g * DIM + j] / cnt;
    __syncthreads();
    float s = b1[j];
    for (int k = 0; k < DIM; k++) s += p[k] * W1[k * DIM + j];
    hh[j] = s;
    __syncthreads();
    if (j < CLS) {
        float l = b2[j];
        for (int k = 0; k < DIM; k++) l += hh[k] * W2[k * CLS + j];
        float mx = l;
#pragma unroll
        for (int m = 16; m >= 1; m >>= 1) mx = fmaxf(mx, __shfl_xor(mx, m, 64));
        float ex = expf(l - mx);
        float se = ex;
#pragma unroll
        for (int m = 16; m >= 1; m >>= 1) se += __shfl_xor(se, m, 64);
        out[g * CLS + j] = l - mx - logf(se);
    }
}

// ---- launch ----------------------------------------------------------------

extern "C" void kernel_launch(void* const* d_in, const int* in_sizes, int n_in,
                              void* d_out, int out_size, void* d_ws, size_t ws_size,
                              hipStream_t stream) {
    (void)in_sizes; (void)n_in; (void)out_size; (void)ws_size;
    const float* x     = (const float*)d_in[0];
    const float* Wself = (const float*)d_in[1];
    const float* bself = (const float*)d_in[2];
    const float* Wmsg  = (const float*)d_in[3];
    const float* bmsg  = (const float*)d_in[4];
    const float* lng   = (const float*)d_in[5];
    const float* lnb   = (const float*)d_in[6];
    const float* W1    = (const float*)d_in[7];
    const float* b1    = (const float*)d_in[8];
    const float* W2    = (const float*)d_in[9];
    const float* b2    = (const float*)d_in[10];
    const int*   ei    = (const int*)d_in[11];
    const int*   batch = (const int*)d_in[12];
    const int* esrc = ei;
    const int* edst = ei + N_EDGES;

    char* w = (char*)d_ws;
    size_t o = 0;
    auto alloc = [&](size_t bytes) { void* p = w + o; o += (bytes + 255) & ~(size_t)255; return p; };
    const size_t XSZ = (size_t)CHK * ROWS1 * CW * 2;  // 12.8 MB chunk-major
    __hip_bfloat16* XbIn = (__hip_bfloat16*)alloc(XSZ);
    __hip_bfloat16* Xb0  = (__hip_bfloat16*)alloc(XSZ);
    __hip_bfloat16* Xb1  = (__hip_bfloat16*)alloc(XSZ);
    __hip_bfloat16* Sg   = (__hip_bfloat16*)alloc(XSZ);
    __hip_bfloat16* WTf  = (__hip_bfloat16*)alloc((size_t)3 * 32768 * 2);
    int*   counts = (int*)alloc((size_t)N_NODES * 4);
    int*   offs   = (int*)alloc((size_t)(N_NODES + 1) * 4);
    int*   ecur   = (int*)alloc((size_t)NBLK * 4);
    int*   ebuf   = (int*)alloc((size_t)NBLK * EB_STRIDE * 4);
    unsigned short* csr = (unsigned short*)alloc((size_t)NBLK * LCAP * 2);
    float* gsum   = (float*)alloc((size_t)NGRAPH * DIM * 4);

    // fused prep: chunk-major bf16 convert + WTf shuffle + zero scratch/pads
    prep_kernel<<<(N_NODES * DIM / 2 + 255) / 256, 256, 0, stream>>>(
        x, Wself, Wmsg, XbIn, WTf, ecur, gsum, XbIn, Xb0, Xb1, Sg);

    // CSR build: bucket -> fused(hist+scan+build), fixed per-bucket stride
    bucket_kernel<<<ABLK, 1024, 0, stream>>>(esrc, edst, ecur, ebuf);
    csr_fused_kernel<<<NBLK, 1024, 0, stream>>>(ebuf, ecur, counts, offs, csr);

    const __hip_bfloat16* XbCur = XbIn;
    __hip_bfloat16* bbufs[3] = {Xb0, Xb1, Xb0};
    for (int i = 0; i < 3; i++) {
        agg_kernel<<<8 * SLOTH, 1024, 0, stream>>>(XbCur, offs, counts, csr, Sg);
        layer_mfma_kernel<<<(N_NODES + 63) / 64, 256, 0, stream>>>(
            XbCur, Sg, WTf + (size_t)i * 32768,
            bself + i * DIM, bmsg + i * DIM, counts,
            (i < 2) ? lng + i * DIM : lng, (i < 2) ? lnb + i * DIM : lnb,
            batch, gsum,
            bbufs[i], (i < 2) ? 1 : 0, (i == 2) ? 1 : 0);
        XbCur = bbufs[i];
    }

    head_kernel<<<NGRAPH, 128, 0, stream>>>(gsum, batch, W1, b1, W2, b2, (float*)d_out);
}

// Round 6
// 300.380 us; speedup vs baseline: 1.1942x; 1.0963x over previous
//
#include <hip/hip_runtime.h>
#include <hip/hip_bf16.h>
#include <math.h>

#define N_NODES 50000
#define N_EDGES 800000
#define DIM 128
#define CLS 32
#define NGRAPH 64
#define LN_EPS 1e-5f
#define NBLK 196                         // dst-buckets of 256 nodes
#define ABLK 256                         // phase-A blocks (1 per CU)
#define EPB (N_EDGES / ABLK)             // 3125 edges per phase-A block
#define EB_STRIDE 7168                   // per-bucket ebuf capacity
#define LCAP 8192                        // per-bucket CSR capacity (fixed stride)
#define ROWS1 (N_NODES + 1)              // 50001 (incl zero pad row)
#define CHK 4                            // feature chunks
#define CW 32                            // features per chunk (64 B rows)
#define NPW 4                            // nodes per agg wave (4 chains in flight)
#define NPB2 (16 * NPW)                  // 64 nodes per 1024-thread agg block
#define NCB ((N_NODES + NPB2 - 1) / NPB2)  // 782 node-blocks per chunk
#define SLOTH ((NCB + 1) / 2)            // 391 node-blocks per XCD slot
#define NPAD (NCB * NPB2)                // 50048 padded node-meta entries

typedef __attribute__((ext_vector_type(8))) short bf16x8;
typedef __attribute__((ext_vector_type(4))) float f32x4;
typedef __attribute__((ext_vector_type(2))) unsigned int u32x2;

static __device__ __forceinline__ int lower_bound_i(const int* a, int n, int key) {
    int lo = 0, hi = n;
    while (lo < hi) { int mid = (lo + hi) >> 1; if (a[mid] < key) lo = mid + 1; else hi = mid; }
    return lo;
}

// accumulate 4 bf16 (one u32x2) into 4 f32
static __device__ __forceinline__ void acc4(float* ac, u32x2 v) {
    union { unsigned int b; float f; } lo0, hi0, lo1, hi1;
    lo0.b = v.x << 16;
    hi0.b = v.x & 0xffff0000u;
    lo1.b = v.y << 16;
    hi1.b = v.y & 0xffff0000u;
    ac[0] += lo0.f;
    ac[1] += hi0.f;
    ac[2] += lo1.f;
    ac[3] += hi1.f;
}

// ---- fused prep: chunk-major bf16 convert + weight fragment shuffle --------
// Node buffers chunk-major [CHK][ROWS1][CW]; chunk c = features c*32..c*32+31.

__global__ __launch_bounds__(256) void prep_kernel(
    const float* __restrict__ x, const float* __restrict__ Wself,
    const float* __restrict__ Wmsg, __hip_bfloat16* __restrict__ XbIn,
    __hip_bfloat16* __restrict__ WTf,
    int* __restrict__ ecur, float* __restrict__ gsum,
    int* __restrict__ off, int* __restrict__ offe,
    __hip_bfloat16* __restrict__ padA, __hip_bfloat16* __restrict__ padB,
    __hip_bfloat16* __restrict__ padC, __hip_bfloat16* __restrict__ padD) {
    int i = blockIdx.x * 256 + threadIdx.x;  // grid covers N_NODES*DIM/2 = 3.2M
    if (i < N_NODES * DIM / 2) {
        float2 v = ((const float2*)x)[i];
        int n = i >> 6, kk = i & 63;          // kk indexes feature pairs
        int c = kk >> 4;
        __hip_bfloat162 hv = __float22bfloat162_rn(v);
        __builtin_nontemporal_store(*(unsigned int*)&hv,
            (unsigned int*)XbIn + ((size_t)c * ROWS1 + n) * 16 + (kk & 15));
    }
    if (i < 3 * 32768) {
        int l = i >> 15;
        int rem = i & 32767;
        int ct = rem >> 12;
        int kk = (rem >> 9) & 7;
        int lane = (rem >> 3) & 63;
        int e = rem & 7;
        int q = lane >> 4, l15 = lane & 15;
        int n = ct * 16 + l15;
        int k = kk * 32 + q * 8 + e;
        float v = (k < 128) ? Wself[l * 16384 + k * 128 + n]
                            : Wmsg[l * 16384 + (k - 128) * 128 + n];
        WTf[i] = __float2bfloat16(v);
    }
    if (i < NBLK) ecur[i] = i * EB_STRIDE;
    if (i < NGRAPH * DIM) gsum[i] = 0.f;
    if (i >= N_NODES && i < NPAD) { off[i] = 0; offe[i] = 0; }  // pad node meta
    if (i < 4 * CHK * CW) {  // zero pad row (n = N_NODES) in every chunk
        __hip_bfloat16* bufs[4] = {padA, padB, padC, padD};
        int buf = i >> 7, c = (i >> 5) & 3, e = i & 31;
        bufs[buf][((size_t)c * ROWS1 + N_NODES) * CW + e] = __float2bfloat16(0.f);
    }
}

// ---- phase A: bucket edges by dst>>8, line-exclusive reservations ----------

__global__ __launch_bounds__(1024) void bucket_kernel(
    const int* __restrict__ esrc, const int* __restrict__ edst,
    int* __restrict__ ecur, int* __restrict__ ebuf) {
    __shared__ int bc4[4][NBLK];
    __shared__ int bc[NBLK], bres[NBLK], bcnt[NBLK];
    const int t = threadIdx.x;
    const int e0 = blockIdx.x * EPB;
    for (int i = t; i < 4 * NBLK; i += 1024) ((int*)bc4)[i] = 0;
    __syncthreads();
    int dr[4], sr[4];
#pragma unroll
    for (int it = 0; it < 4; it++) {
        int i = t + it * 1024;
        if (i < EPB) { dr[it] = edst[e0 + i]; sr[it] = esrc[e0 + i]; }
        else { dr[it] = -1; sr[it] = 0; }
    }
    const int cpy = (t >> 6) & 3;
#pragma unroll
    for (int it = 0; it < 4; it++)
        if (dr[it] >= 0) atomicAdd(&bc4[cpy][dr[it] >> 8], 1);
    __syncthreads();
    if (t < NBLK) {
        int c = bc4[0][t] + bc4[1][t] + bc4[2][t] + bc4[3][t];
        int r = (c + 7) & ~7;                   // pad to multiple of 8
        int res = atomicAdd(&ecur[t], r);       // one global atomic per (block,bucket)
        bres[t] = res;
        bcnt[t] = c;
        bc[t] = res;
    }
    __syncthreads();
#pragma unroll
    for (int it = 0; it < 4; it++)
        if (dr[it] >= 0) {
            int d = dr[it];
            int pos = atomicAdd(&bc[d >> 8], 1);
            ebuf[pos] = ((d & 255) << 16) | sr[it];  // src < 50000 < 2^16
        }
    __syncthreads();
    if (t < NBLK) {
        int c = bcnt[t], r = (c + 7) & ~7, base = bres[t];
        for (int j = c; j < r; j++) ebuf[base + j] = -1;  // sentinels
    }
}

// ---- phase B (fused): per-bucket hist + scan + CSR build in LDS ------------
// csr stored as ushort (src < 2^16); pad entries point at zero row N_NODES.
// Also writes offe[] = off + padded count (agg consumes off/offe via s_load).

__global__ __launch_bounds__(1024) void csr_fused_kernel(
    const int* __restrict__ ebuf, const int* __restrict__ ecur,
    int* __restrict__ counts, int* __restrict__ off, int* __restrict__ offe,
    unsigned short* __restrict__ csr) {
    __shared__ int ncnt[256];
    __shared__ int ssc[256];
    __shared__ int cur[256];
    __shared__ unsigned short lcsr[LCAP];
    const int b = blockIdx.x, t = threadIdx.x;
    const int used = ecur[b] - b * EB_STRIDE;
    const int* eb = ebuf + b * EB_STRIDE;
    for (int i = t; i < LCAP / 2; i += 1024)
        ((unsigned int*)lcsr)[i] = 0xC350C350u;  // 50000 | 50000<<16
    if (t < 256) ncnt[t] = 0;
    __syncthreads();
    for (int i = t; i < used; i += 1024) {
        int p = eb[i];
        if (p != -1) atomicAdd(&ncnt[p >> 16], 1);
    }
    __syncthreads();
    int myc = 0, mypad = 0;
    const int gi = b * 256 + t;
    if (t < 256) {
        myc = (gi < N_NODES) ? ncnt[t] : 0;
        mypad = (myc + 7) & ~7;
        ssc[t] = mypad;
    }
    __syncthreads();
    for (int o = 1; o < 256; o <<= 1) {
        int v = 0;
        if (t < 256 && t >= o) v = ssc[t - o];
        __syncthreads();
        if (t < 256) ssc[t] += v;
        __syncthreads();
    }
    if (t < 256) {
        int eoff = ssc[t] - mypad;
        cur[t] = eoff;
        if (gi < N_NODES) {
            off[gi] = b * LCAP + eoff;
            offe[gi] = b * LCAP + eoff + mypad;
            counts[gi] = myc;
        }
    }
    __syncthreads();
    for (int i = t; i < used; i += 1024) {
        int p = eb[i];
        if (p != -1) {
            int pos = atomicAdd(&cur[p >> 16], 1);
            lcsr[pos] = (unsigned short)(p & 0xFFFF);
        }
    }
    __syncthreads();
    const int total = ssc[255];                 // multiple of 8
    int4* dst4 = (int4*)(csr + (size_t)b * LCAP);
    const int4* src4 = (const int4*)lcsr;
    for (int i = t; i < (total >> 3); i += 1024) dst4[i] = src4[i];
}

// ---- agg v6: XCD-pinned chunked gather, 1-hop chain, scalar control --------
// blockIdx%8 ~ XCD; chunk = slot&3 (proven: FETCH 55->17.5 MB).
// Per 16-edge round per node: lane group g8 reads BOTH its edge indices with
// one group-shared uint load (HW broadcast, no shfl/DS), then two 8 B gathers
// at SGPR-base + 32-bit voffset. off/offe via s_load (wave-uniform n).
// Rounds are PREDICATED per node (uniform SALU mask), not all-or-break, so
// drains of uneven-degree nodes stay pipelined 4-wide.

__global__ __launch_bounds__(1024) void agg_kernel(
    const __hip_bfloat16* __restrict__ Xg, const int* __restrict__ off,
    const int* __restrict__ offe, const unsigned short* __restrict__ csr,
    __hip_bfloat16* __restrict__ Sg) {
    const int b = blockIdx.x;
    const int slot = b & 7;
    const int chunk = slot & 3;
    const int half = slot >> 2;
    const int nbidx = (b >> 3) * 2 + half;      // [0, NCB)
    const int w = __builtin_amdgcn_readfirstlane(threadIdx.x >> 6);
    const int lane = threadIdx.x & 63;
    const int l8 = lane & 7, g8 = lane >> 3;
    const char* X = (const char*)(Xg + (size_t)chunk * ROWS1 * CW);
    const int nbase = nbidx * NPB2 + w * NPW;   // SGPR
    const int loff = l8 * 8;                    // byte offset within 64 B row
    const int coff = g8 * 4;                    // byte offset into csr uint pair

    int bj[NPW], ej[NPW];
    float ac[NPW][4];
#pragma unroll
    for (int j = 0; j < NPW; j++) {
        int n = nbase + j;                      // < NPAD; pads have off==offe==0
        bj[j] = off[n];
        ej[j] = offe[n];
        ac[j][0] = ac[j][1] = ac[j][2] = ac[j][3] = 0.f;
    }
    for (;;) {
        int act = 0;
#pragma unroll
        for (int j = 0; j < NPW; j++) act |= (bj[j] + 16 <= ej[j]) ? (1 << j) : 0;
        if (!act) break;
        unsigned int u[NPW];
#pragma unroll
        for (int j = 0; j < NPW; j++)
            if (act & (1 << j))
                u[j] = *(const unsigned int*)((const char*)(csr + bj[j]) + coff);
        u32x2 v0[NPW], v1[NPW];
#pragma unroll
        for (int j = 0; j < NPW; j++)
            if (act & (1 << j)) {
                int s0 = u[j] & 0xffff, s1 = u[j] >> 16;
                v0[j] = *(const u32x2*)(X + ((s0 << 6) | loff));
                v1[j] = *(const u32x2*)(X + ((s1 << 6) | loff));
            }
#pragma unroll
        for (int j = 0; j < NPW; j++)
            if (act & (1 << j)) {
                acc4(ac[j], v0[j]);
                acc4(ac[j], v1[j]);
                bj[j] += 16;
            }
    }
    // 8-edge tails (padded: remaining is exactly 0 or 8)
    {
        unsigned int u[NPW];
        int tact = 0;
#pragma unroll
        for (int j = 0; j < NPW; j++)
            if (bj[j] < ej[j]) {
                tact |= (1 << j);
                u[j] = csr[bj[j] + g8];
            }
#pragma unroll
        for (int j = 0; j < NPW; j++)
            if (tact & (1 << j)) {
                u32x2 v = *(const u32x2*)(X + (((int)u[j] << 6) | loff));
                acc4(ac[j], v);
            }
    }
    // reduce across the 8 lane-groups (lane bits 3,4,5)
#pragma unroll
    for (int j = 0; j < NPW; j++)
#pragma unroll
        for (int k = 0; k < 4; k++) {
            ac[j][k] += __shfl_xor(ac[j][k], 8, 64);
            ac[j][k] += __shfl_xor(ac[j][k], 16, 64);
            ac[j][k] += __shfl_xor(ac[j][k], 32, 64);
        }
    if (lane < 8) {
#pragma unroll
        for (int j = 0; j < NPW; j++) {
            int n = nbase + j;
            if (n < N_NODES) {
                union { u32x2 u; __hip_bfloat162 h[2]; } pk;
                pk.h[0] = __float22bfloat162_rn(make_float2(ac[j][0], ac[j][1]));
                pk.h[1] = __float22bfloat162_rn(make_float2(ac[j][2], ac[j][3]));
                __builtin_nontemporal_store(pk.u,
                    (u32x2*)(Sg + ((size_t)chunk * ROWS1 + n) * CW + lane * 4));
            }
        }
    }
}

// ---- layer: MFMA H = [Xg|Sg] @ WTf^T; +bias+deg*bmsg, ReLU, LN, pool -------
// No LDS, no barriers: A-fragments chunk-major from global (fragment ks ==
// chunk ks), B-fragments fragment-ordered from WTf. Xout stores nontemporal.

__global__ __launch_bounds__(256) void layer_mfma_kernel(
    const __hip_bfloat16* __restrict__ Xg, const __hip_bfloat16* __restrict__ Sg,
    const __hip_bfloat16* __restrict__ WTf,  // fragment-ordered, this layer
    const float* __restrict__ bself, const float* __restrict__ bmsg,
    const int* __restrict__ counts,
    const float* __restrict__ lng, const float* __restrict__ lnb,
    const int* __restrict__ batch, float* __restrict__ gsum,
    __hip_bfloat16* __restrict__ Xout, int do_ln, int do_pool) {
    const int tid = threadIdx.x;
    const int w = tid >> 6, lane = tid & 63;
    const int l15 = lane & 15, q = lane >> 4;
    const int growbase = blockIdx.x * 64 + w * 16;
    const int row = growbase + l15;
    const int rowc = min(row, N_NODES);  // pad row N_NODES is all zeros

    f32x4 acc[8];
#pragma unroll
    for (int ct = 0; ct < 8; ct++) acc[ct] = (f32x4){0.f, 0.f, 0.f, 0.f};

#pragma unroll
    for (int ks = 0; ks < 4; ks++) {
        bf16x8 afrag = *(const bf16x8*)(Xg + ((size_t)ks * ROWS1 + rowc) * CW + q * 8);
#pragma unroll
        for (int ct = 0; ct < 8; ct++) {
            bf16x8 bfrag = *(const bf16x8*)(WTf + (((ct * 8 + ks) * 64) + lane) * 8);
            acc[ct] = __builtin_amdgcn_mfma_f32_16x16x32_bf16(afrag, bfrag, acc[ct], 0, 0, 0);
        }
    }
#pragma unroll
    for (int ks = 0; ks < 4; ks++) {
        bf16x8 afrag = *(const bf16x8*)(Sg + ((size_t)ks * ROWS1 + rowc) * CW + q * 8);
#pragma unroll
        for (int ct = 0; ct < 8; ct++) {
            bf16x8 bfrag = *(const bf16x8*)(WTf + (((ct * 8 + 4 + ks) * 64) + lane) * 8);
            acc[ct] = __builtin_amdgcn_mfma_f32_16x16x32_bf16(afrag, bfrag, acc[ct], 0, 0, 0);
        }
    }

    // ---- epilogue: lane holds rows (q*4+r), cols (ct*16+l15) ----
    float racc[8];
#pragma unroll
    for (int ct = 0; ct < 8; ct++) racc[ct] = 0.f;
    int gw = 0;
    bool fastp = false;
    if (do_pool) {
        int first = (growbase < N_NODES) ? growbase : (N_NODES - 1);
        gw = batch[first];
        int lastrow = growbase + 15;
        fastp = (growbase < N_NODES) && (lastrow < N_NODES) && (batch[lastrow] == gw);
    }
#pragma unroll
    for (int r = 0; r < 4; r++) {
        int grow = growbase + q * 4 + r;
        bool valid = grow < N_NODES;
        float dg = valid ? (float)counts[grow] : 0.f;
        float v[8];
        float s1 = 0.f;
#pragma unroll
        for (int ct = 0; ct < 8; ct++) {
            int col = ct * 16 + l15;
            float h = acc[ct][r] + bself[col] + dg * bmsg[col];
            h = fmaxf(h, 0.f);
            v[ct] = h;
            s1 += h;
        }
        if (do_ln) {
#pragma unroll
            for (int m = 1; m < 16; m <<= 1) s1 += __shfl_xor(s1, m, 64);
            float mu = s1 * (1.0f / 128.0f);
            float s2 = 0.f;
#pragma unroll
            for (int ct = 0; ct < 8; ct++) { float d = v[ct] - mu; s2 += d * d; }
#pragma unroll
            for (int m = 1; m < 16; m <<= 1) s2 += __shfl_xor(s2, m, 64);
            float rs = rsqrtf(s2 * (1.0f / 128.0f) + LN_EPS);
#pragma unroll
            for (int ct = 0; ct < 8; ct++) {
                int col = ct * 16 + l15;
                v[ct] = lng[col] * (v[ct] - mu) * rs + lnb[col];
            }
        }
        if (do_pool) {
            if (fastp) {
#pragma unroll
                for (int ct = 0; ct < 8; ct++) racc[ct] += v[ct];
            } else if (valid) {
                int g = batch[grow];
#pragma unroll
                for (int ct = 0; ct < 8; ct++)
                    atomicAdd(&gsum[g * DIM + ct * 16 + l15], v[ct]);
            }
        } else if (valid) {
            // chunk-major store: col = ct*16+l15 -> chunk ct>>1, elem (ct&1)*16+l15
#pragma unroll
            for (int ct = 0; ct < 8; ct++) {
                __hip_bfloat16 hv = __float2bfloat16(v[ct]);
                __builtin_nontemporal_store(*(unsigned short*)&hv,
                    (unsigned short*)Xout +
                        ((size_t)(ct >> 1) * ROWS1 + grow) * CW + (ct & 1) * 16 + l15);
            }
        }
    }
    if (do_pool && fastp) {
#pragma unroll
        for (int ct = 0; ct < 8; ct++) {
            racc[ct] += __shfl_xor(racc[ct], 16, 64);
            racc[ct] += __shfl_xor(racc[ct], 32, 64);
        }
        if (q == 0) {
#pragma unroll
            for (int ct = 0; ct < 8; ct++)
                atomicAdd(&gsum[gw * DIM + ct * 16 + l15], racc[ct]);
        }
    }
}

// ---- head: mean + MLP + log_softmax ----------------------------------------

__global__ __launch_bounds__(128) void head_kernel(
    const float* __restrict__ gsum, const int* __restrict__ batch,
    const float* __restrict__ W1, const float* __restrict__ b1,
    const float* __restrict__ W2, const float* __restrict__ b2,
    float* __restrict__ out) {
    __shared__ float p[128];
    __shared__ float hh[128];
    int g = blockIdx.x;
    int j = threadIdx.x;
    int lo = lower_bound_i(batch, N_NODES, g);
    int hi = lower_bound_i(batch, N_NODES, g + 1);
    float cnt = fmaxf((float)(hi - lo), 1.0f);
    p[j] = gsum[g * DIM + j] / cnt;
    __syncthreads();
    float s = b1[j];
    for (int k = 0; k < DIM; k++) s += p[k] * W1[k * DIM + j];
    hh[j] = s;
    __syncthreads();
    if (j < CLS) {
        float l = b2[j];
        for (int k = 0; k < DIM; k++) l += hh[k] * W2[k * CLS + j];
        float mx = l;
#pragma unroll
        for (int m = 16; m >= 1; m >>= 1) mx = fmaxf(mx, __shfl_xor(mx, m, 64));
        float ex = expf(l - mx);
        float se = ex;
#pragma unroll
        for (int m = 16; m >= 1; m >>= 1) se += __shfl_xor(se, m, 64);
        out[g * CLS + j] = l - mx - logf(se);
    }
}

// ---- launch ----------------------------------------------------------------

extern "C" void kernel_launch(void* const* d_in, const int* in_sizes, int n_in,
                              void* d_out, int out_size, void* d_ws, size_t ws_size,
                              hipStream_t stream) {
    (void)in_sizes; (void)n_in; (void)out_size; (void)ws_size;
    const float* x     = (const float*)d_in[0];
    const float* Wself = (const float*)d_in[1];
    const float* bself = (const float*)d_in[2];
    const float* Wmsg  = (const float*)d_in[3];
    const float* bmsg  = (const float*)d_in[4];
    const float* lng   = (const float*)d_in[5];
    const float* lnb   = (const float*)d_in[6];
    const float* W1    = (const float*)d_in[7];
    const float* b1    = (const float*)d_in[8];
    const float* W2    = (const float*)d_in[9];
    const float* b2    = (const float*)d_in[10];
    const int*   ei    = (const int*)d_in[11];
    const int*   batch = (const int*)d_in[12];
    const int* esrc = ei;
    const int* edst = ei + N_EDGES;

    char* w = (char*)d_ws;
    size_t o = 0;
    auto alloc = [&](size_t bytes) { void* p = w + o; o += (bytes + 255) & ~(size_t)255; return p; };
    const size_t XSZ = (size_t)CHK * ROWS1 * CW * 2;  // 12.8 MB chunk-major
    __hip_bfloat16* XbIn = (__hip_bfloat16*)alloc(XSZ);
    __hip_bfloat16* Xb0  = (__hip_bfloat16*)alloc(XSZ);
    __hip_bfloat16* Xb1  = (__hip_bfloat16*)alloc(XSZ);
    __hip_bfloat16* Sg   = (__hip_bfloat16*)alloc(XSZ);
    __hip_bfloat16* WTf  = (__hip_bfloat16*)alloc((size_t)3 * 32768 * 2);
    int*   counts = (int*)alloc((size_t)N_NODES * 4);
    int*   offs   = (int*)alloc((size_t)NPAD * 4);
    int*   offe   = (int*)alloc((size_t)NPAD * 4);
    int*   ecur   = (int*)alloc((size_t)NBLK * 4);
    int*   ebuf   = (int*)alloc((size_t)NBLK * EB_STRIDE * 4);
    unsigned short* csr = (unsigned short*)alloc((size_t)NBLK * LCAP * 2);
    float* gsum   = (float*)alloc((size_t)NGRAPH * DIM * 4);

    // fused prep: chunk-major bf16 convert + WTf shuffle + zero scratch/pads
    prep_kernel<<<(N_NODES * DIM / 2 + 255) / 256, 256, 0, stream>>>(
        x, Wself, Wmsg, XbIn, WTf, ecur, gsum, offs, offe, XbIn, Xb0, Xb1, Sg);

    // CSR build: bucket -> fused(hist+scan+build), fixed per-bucket stride
    bucket_kernel<<<ABLK, 1024, 0, stream>>>(esrc, edst, ecur, ebuf);
    csr_fused_kernel<<<NBLK, 1024, 0, stream>>>(ebuf, ecur, counts, offs, offe, csr);

    const __hip_bfloat16* XbCur = XbIn;
    __hip_bfloat16* bbufs[3] = {Xb0, Xb1, Xb0};
    for (int i = 0; i < 3; i++) {
        agg_kernel<<<8 * SLOTH, 1024, 0, stream>>>(XbCur, offs, offe, csr, Sg);
        layer_mfma_kernel<<<(N_NODES + 63) / 64, 256, 0, stream>>>(
            XbCur, Sg, WTf + (size_t)i * 32768,
            bself + i * DIM, bmsg + i * DIM, counts,
            (i < 2) ? lng + i * DIM : lng, (i < 2) ? lnb + i * DIM : lnb,
            batch, gsum,
            bbufs[i], (i < 2) ? 1 : 0, (i == 2) ? 1 : 0);
        XbCur = bbufs[i];
    }

    head_kernel<<<NGRAPH, 128, 0, stream>>>(gsum, batch, W1, b1, W2, b2, (float*)d_out);
}

// Round 7
// 281.709 us; speedup vs baseline: 1.2734x; 1.0663x over previous
//
#include <hip/hip_runtime.h>
#include <hip/hip_bf16.h>
#include <math.h>

#define N_NODES 50000
#define N_EDGES 800000
#define DIM 128
#define CLS 32
#define NGRAPH 64
#define LN_EPS 1e-5f
#define NBLK 196                         // dst-buckets of 256 nodes
#define ABLK 256                         // phase-A blocks (1 per CU)
#define EPB (N_EDGES / ABLK)             // 3125 edges per phase-A block
#define EB_STRIDE 7168                   // per-bucket ebuf capacity
#define LCAP 8192                        // per-bucket CSR capacity (fixed stride)
#define ROWS1 (N_NODES + 1)              // 50001 (incl zero pad row)
#define CHK 4                            // feature chunks
#define CW 32                            // features per chunk (64 B rows)
#define NPW 4                            // nodes per agg wave (4 chains in flight)
#define NPB2 (16 * NPW)                  // 64 nodes per 1024-thread agg block
#define NCB ((N_NODES + NPB2 - 1) / NPB2)  // 782 node-blocks per chunk
#define SLOTH ((NCB + 1) / 2)            // 391 node-blocks per XCD slot
#define NPAD (NCB * NPB2)                // 50048 padded node-meta entries

typedef __attribute__((ext_vector_type(8))) short bf16x8;
typedef __attribute__((ext_vector_type(4))) float f32x4;
typedef __attribute__((ext_vector_type(2))) unsigned int u32x2;

static __device__ __forceinline__ int lower_bound_i(const int* a, int n, int key) {
    int lo = 0, hi = n;
    while (lo < hi) { int mid = (lo + hi) >> 1; if (a[mid] < key) lo = mid + 1; else hi = mid; }
    return lo;
}

// accumulate 4 bf16 (one u32x2) into 4 f32
static __device__ __forceinline__ void acc4(float* ac, u32x2 v) {
    union { unsigned int b; float f; } lo0, hi0, lo1, hi1;
    lo0.b = v.x << 16;
    hi0.b = v.x & 0xffff0000u;
    lo1.b = v.y << 16;
    hi1.b = v.y & 0xffff0000u;
    ac[0] += lo0.f;
    ac[1] += hi0.f;
    ac[2] += lo1.f;
    ac[3] += hi1.f;
}

// ---- fused prep: chunk-major bf16 convert + weight fragment shuffle --------
// Node buffers chunk-major [CHK][ROWS1][CW]; chunk c = features c*32..c*32+31.
// WTf per layer: [half(2)][ct(8)][ks(4)][lane(64)][e(8)] -- half 0 = Wself,
// half 1 = Wmsg; n = ct*16+(lane&15), k = half*128 + ks*32 + (lane>>4)*8 + e.
// Each half is one contiguous 32 KB slab (block-stageable with one memcpy).

__global__ __launch_bounds__(256) void prep_kernel(
    const float* __restrict__ x, const float* __restrict__ Wself,
    const float* __restrict__ Wmsg, __hip_bfloat16* __restrict__ XbIn,
    __hip_bfloat16* __restrict__ WTf,
    int* __restrict__ ecur, float* __restrict__ gsum,
    int* __restrict__ off, int* __restrict__ offe,
    __hip_bfloat16* __restrict__ padA, __hip_bfloat16* __restrict__ padB,
    __hip_bfloat16* __restrict__ padC, __hip_bfloat16* __restrict__ padD) {
    int i = blockIdx.x * 256 + threadIdx.x;  // grid covers N_NODES*DIM/2 = 3.2M
    if (i < N_NODES * DIM / 2) {
        float2 v = ((const float2*)x)[i];
        int n = i >> 6, kk = i & 63;          // kk indexes feature pairs
        int c = kk >> 4;
        __hip_bfloat162 hv = __float22bfloat162_rn(v);
        __builtin_nontemporal_store(*(unsigned int*)&hv,
            (unsigned int*)XbIn + ((size_t)c * ROWS1 + n) * 16 + (kk & 15));
    }
    if (i < 3 * 32768) {
        int l = i >> 15;
        int rem = i & 32767;
        int half = rem >> 14;
        int rem2 = rem & 16383;
        int ct = rem2 >> 11;
        int ks = (rem2 >> 9) & 3;
        int lane = (rem2 >> 3) & 63;
        int e = rem2 & 7;
        int q = lane >> 4, l15 = lane & 15;
        int n = ct * 16 + l15;
        int k = half * 128 + ks * 32 + q * 8 + e;
        float v = (k < 128) ? Wself[l * 16384 + k * 128 + n]
                            : Wmsg[l * 16384 + (k - 128) * 128 + n];
        WTf[i] = __float2bfloat16(v);
    }
    if (i < NBLK) ecur[i] = i * EB_STRIDE;
    if (i < NGRAPH * DIM) gsum[i] = 0.f;
    if (i >= N_NODES && i < NPAD) { off[i] = 0; offe[i] = 0; }  // pad node meta
    if (i < 4 * CHK * CW) {  // zero pad row (n = N_NODES) in every chunk
        __hip_bfloat16* bufs[4] = {padA, padB, padC, padD};
        int buf = i >> 7, c = (i >> 5) & 3, e = i & 31;
        bufs[buf][((size_t)c * ROWS1 + N_NODES) * CW + e] = __float2bfloat16(0.f);
    }
}

// ---- phase A: bucket edges by dst>>8, line-exclusive reservations ----------

__global__ __launch_bounds__(1024) void bucket_kernel(
    const int* __restrict__ esrc, const int* __restrict__ edst,
    int* __restrict__ ecur, int* __restrict__ ebuf) {
    __shared__ int bc4[4][NBLK];
    __shared__ int bc[NBLK], bres[NBLK], bcnt[NBLK];
    const int t = threadIdx.x;
    const int e0 = blockIdx.x * EPB;
    for (int i = t; i < 4 * NBLK; i += 1024) ((int*)bc4)[i] = 0;
    __syncthreads();
    int dr[4], sr[4];
#pragma unroll
    for (int it = 0; it < 4; it++) {
        int i = t + it * 1024;
        if (i < EPB) { dr[it] = edst[e0 + i]; sr[it] = esrc[e0 + i]; }
        else { dr[it] = -1; sr[it] = 0; }
    }
    const int cpy = (t >> 6) & 3;
#pragma unroll
    for (int it = 0; it < 4; it++)
        if (dr[it] >= 0) atomicAdd(&bc4[cpy][dr[it] >> 8], 1);
    __syncthreads();
    if (t < NBLK) {
        int c = bc4[0][t] + bc4[1][t] + bc4[2][t] + bc4[3][t];
        int r = (c + 7) & ~7;                   // pad to multiple of 8
        int res = atomicAdd(&ecur[t], r);       // one global atomic per (block,bucket)
        bres[t] = res;
        bcnt[t] = c;
        bc[t] = res;
    }
    __syncthreads();
#pragma unroll
    for (int it = 0; it < 4; it++)
        if (dr[it] >= 0) {
            int d = dr[it];
            int pos = atomicAdd(&bc[d >> 8], 1);
            ebuf[pos] = ((d & 255) << 16) | sr[it];  // src < 50000 < 2^16
        }
    __syncthreads();
    if (t < NBLK) {
        int c = bcnt[t], r = (c + 7) & ~7, base = bres[t];
        for (int j = c; j < r; j++) ebuf[base + j] = -1;  // sentinels
    }
}

// ---- phase B (fused): per-bucket hist + scan + CSR build in LDS ------------
// csr stored as ushort (src < 2^16); pad entries point at zero row N_NODES.
// Also writes offe[] = off + padded count (agg consumes off/offe via s_load).

__global__ __launch_bounds__(1024) void csr_fused_kernel(
    const int* __restrict__ ebuf, const int* __restrict__ ecur,
    int* __restrict__ counts, int* __restrict__ off, int* __restrict__ offe,
    unsigned short* __restrict__ csr) {
    __shared__ int ncnt[256];
    __shared__ int ssc[256];
    __shared__ int cur[256];
    __shared__ unsigned short lcsr[LCAP];
    const int b = blockIdx.x, t = threadIdx.x;
    const int used = ecur[b] - b * EB_STRIDE;
    const int* eb = ebuf + b * EB_STRIDE;
    for (int i = t; i < LCAP / 2; i += 1024)
        ((unsigned int*)lcsr)[i] = 0xC350C350u;  // 50000 | 50000<<16
    if (t < 256) ncnt[t] = 0;
    __syncthreads();
    for (int i = t; i < used; i += 1024) {
        int p = eb[i];
        if (p != -1) atomicAdd(&ncnt[p >> 16], 1);
    }
    __syncthreads();
    int myc = 0, mypad = 0;
    const int gi = b * 256 + t;
    if (t < 256) {
        myc = (gi < N_NODES) ? ncnt[t] : 0;
        mypad = (myc + 7) & ~7;
        ssc[t] = mypad;
    }
    __syncthreads();
    for (int o = 1; o < 256; o <<= 1) {
        int v = 0;
        if (t < 256 && t >= o) v = ssc[t - o];
        __syncthreads();
        if (t < 256) ssc[t] += v;
        __syncthreads();
    }
    if (t < 256) {
        int eoff = ssc[t] - mypad;
        cur[t] = eoff;
        if (gi < N_NODES) {
            off[gi] = b * LCAP + eoff;
            offe[gi] = b * LCAP + eoff + mypad;
            counts[gi] = myc;
        }
    }
    __syncthreads();
    for (int i = t; i < used; i += 1024) {
        int p = eb[i];
        if (p != -1) {
            int pos = atomicAdd(&cur[p >> 16], 1);
            lcsr[pos] = (unsigned short)(p & 0xFFFF);
        }
    }
    __syncthreads();
    const int total = ssc[255];                 // multiple of 8
    int4* dst4 = (int4*)(csr + (size_t)b * LCAP);
    const int4* src4 = (const int4*)lcsr;
    for (int i = t; i < (total >> 3); i += 1024) dst4[i] = src4[i];
}

// ---- agg: XCD-pinned chunked gather, 1-hop chain, scalar control -----------
// (unchanged from R6: 43.7 us measured, FETCH ~18 MB)

__global__ __launch_bounds__(1024) void agg_kernel(
    const __hip_bfloat16* __restrict__ Xg, const int* __restrict__ off,
    const int* __restrict__ offe, const unsigned short* __restrict__ csr,
    __hip_bfloat16* __restrict__ Sg) {
    const int b = blockIdx.x;
    const int slot = b & 7;
    const int chunk = slot & 3;
    const int half = slot >> 2;
    const int nbidx = (b >> 3) * 2 + half;      // [0, NCB)
    const int w = __builtin_amdgcn_readfirstlane(threadIdx.x >> 6);
    const int lane = threadIdx.x & 63;
    const int l8 = lane & 7, g8 = lane >> 3;
    const char* X = (const char*)(Xg + (size_t)chunk * ROWS1 * CW);
    const int nbase = nbidx * NPB2 + w * NPW;   // SGPR
    const int loff = l8 * 8;                    // byte offset within 64 B row
    const int coff = g8 * 4;                    // byte offset into csr uint pair

    int bj[NPW], ej[NPW];
    float ac[NPW][4];
#pragma unroll
    for (int j = 0; j < NPW; j++) {
        int n = nbase + j;                      // < NPAD; pads have off==offe==0
        bj[j] = off[n];
        ej[j] = offe[n];
        ac[j][0] = ac[j][1] = ac[j][2] = ac[j][3] = 0.f;
    }
    for (;;) {
        int act = 0;
#pragma unroll
        for (int j = 0; j < NPW; j++) act |= (bj[j] + 16 <= ej[j]) ? (1 << j) : 0;
        if (!act) break;
        unsigned int u[NPW];
#pragma unroll
        for (int j = 0; j < NPW; j++)
            if (act & (1 << j))
                u[j] = *(const unsigned int*)((const char*)(csr + bj[j]) + coff);
        u32x2 v0[NPW], v1[NPW];
#pragma unroll
        for (int j = 0; j < NPW; j++)
            if (act & (1 << j)) {
                int s0 = u[j] & 0xffff, s1 = u[j] >> 16;
                v0[j] = *(const u32x2*)(X + ((s0 << 6) | loff));
                v1[j] = *(const u32x2*)(X + ((s1 << 6) | loff));
            }
#pragma unroll
        for (int j = 0; j < NPW; j++)
            if (act & (1 << j)) {
                acc4(ac[j], v0[j]);
                acc4(ac[j], v1[j]);
                bj[j] += 16;
            }
    }
    // 8-edge tails (padded: remaining is exactly 0 or 8)
    {
        unsigned int u[NPW];
        int tact = 0;
#pragma unroll
        for (int j = 0; j < NPW; j++)
            if (bj[j] < ej[j]) {
                tact |= (1 << j);
                u[j] = csr[bj[j] + g8];
            }
#pragma unroll
        for (int j = 0; j < NPW; j++)
            if (tact & (1 << j)) {
                u32x2 v = *(const u32x2*)(X + (((int)u[j] << 6) | loff));
                acc4(ac[j], v);
            }
    }
    // reduce across the 8 lane-groups (lane bits 3,4,5)
#pragma unroll
    for (int j = 0; j < NPW; j++)
#pragma unroll
        for (int k = 0; k < 4; k++) {
            ac[j][k] += __shfl_xor(ac[j][k], 8, 64);
            ac[j][k] += __shfl_xor(ac[j][k], 16, 64);
            ac[j][k] += __shfl_xor(ac[j][k], 32, 64);
        }
    if (lane < 8) {
#pragma unroll
        for (int j = 0; j < NPW; j++) {
            int n = nbase + j;
            if (n < N_NODES) {
                union { u32x2 u; __hip_bfloat162 h[2]; } pk;
                pk.h[0] = __float22bfloat162_rn(make_float2(ac[j][0], ac[j][1]));
                pk.h[1] = __float22bfloat162_rn(make_float2(ac[j][2], ac[j][3]));
                __builtin_nontemporal_store(pk.u,
                    (u32x2*)(Sg + ((size_t)chunk * ROWS1 + n) * CW + lane * 4));
            }
        }
    }
}

// ---- layer: MFMA H = [Xg|Sg] @ W^T with block-staged LDS weights -----------
// B-fragments staged per BLOCK (two 32 KB phases: Wself then Wmsg) instead of
// per-wave global loads -- cuts ~200 MB/layer of L2->L1 B-traffic to 50 MB
// and removes the L2-latency-exposed chain from the MFMA loop. Fragment-order
// LDS layout is conflict-free on write (linear) and read (for fixed (ct,ks)
// all 64 lanes read consecutive 16 B -> ideal b128). LDS 32 KB -> 5 blocks/CU.

__global__ __launch_bounds__(256) void layer_mfma_kernel(
    const __hip_bfloat16* __restrict__ Xg, const __hip_bfloat16* __restrict__ Sg,
    const __hip_bfloat16* __restrict__ WTf,  // [2][8][4][64][8] this layer
    const float* __restrict__ bself, const float* __restrict__ bmsg,
    const int* __restrict__ counts,
    const float* __restrict__ lng, const float* __restrict__ lnb,
    const int* __restrict__ batch, float* __restrict__ gsum,
    __hip_bfloat16* __restrict__ Xout, int do_ln, int do_pool) {
    __shared__ __hip_bfloat16 wlds[16384];     // 32 KB: one half of WTf
    const int tid = threadIdx.x;
    const int w = tid >> 6, lane = tid & 63;
    const int l15 = lane & 15, q = lane >> 4;
    const int growbase = blockIdx.x * 64 + w * 16;
    const int row = growbase + l15;
    const int rowc = min(row, N_NODES);  // pad row N_NODES is all zeros

    f32x4 acc[8];
#pragma unroll
    for (int ct = 0; ct < 8; ct++) acc[ct] = (f32x4){0.f, 0.f, 0.f, 0.f};

    // stage Wself half (32 KB, contiguous, coalesced, conflict-free)
    {
        const uint4* src = (const uint4*)WTf;
        uint4* dst = (uint4*)wlds;
#pragma unroll
        for (int i = 0; i < 8; i++) dst[tid + i * 256] = src[tid + i * 256];
    }
    __syncthreads();
#pragma unroll
    for (int ks = 0; ks < 4; ks++) {
        bf16x8 afrag = *(const bf16x8*)(Xg + ((size_t)ks * ROWS1 + rowc) * CW + q * 8);
#pragma unroll
        for (int ct = 0; ct < 8; ct++) {
            bf16x8 bfrag = *(const bf16x8*)(&wlds[(((ct * 4 + ks) * 64) + lane) * 8]);
            acc[ct] = __builtin_amdgcn_mfma_f32_16x16x32_bf16(afrag, bfrag, acc[ct], 0, 0, 0);
        }
    }
    __syncthreads();
    // stage Wmsg half
    {
        const uint4* src = (const uint4*)(WTf + 16384);
        uint4* dst = (uint4*)wlds;
#pragma unroll
        for (int i = 0; i < 8; i++) dst[tid + i * 256] = src[tid + i * 256];
    }
    __syncthreads();
#pragma unroll
    for (int ks = 0; ks < 4; ks++) {
        bf16x8 afrag = *(const bf16x8*)(Sg + ((size_t)ks * ROWS1 + rowc) * CW + q * 8);
#pragma unroll
        for (int ct = 0; ct < 8; ct++) {
            bf16x8 bfrag = *(const bf16x8*)(&wlds[(((ct * 4 + ks) * 64) + lane) * 8]);
            acc[ct] = __builtin_amdgcn_mfma_f32_16x16x32_bf16(afrag, bfrag, acc[ct], 0, 0, 0);
        }
    }

    // ---- epilogue: lane holds rows (q*4+r), cols (ct*16+l15) ----
    float racc[8];
#pragma unroll
    for (int ct = 0; ct < 8; ct++) racc[ct] = 0.f;
    int gw = 0;
    bool fastp = false;
    if (do_pool) {
        int first = (growbase < N_NODES) ? growbase : (N_NODES - 1);
        gw = batch[first];
        int lastrow = growbase + 15;
        fastp = (growbase < N_NODES) && (lastrow < N_NODES) && (batch[lastrow] == gw);
    }
#pragma unroll
    for (int r = 0; r < 4; r++) {
        int grow = growbase + q * 4 + r;
        bool valid = grow < N_NODES;
        float dg = valid ? (float)counts[grow] : 0.f;
        float v[8];
        float s1 = 0.f;
#pragma unroll
        for (int ct = 0; ct < 8; ct++) {
            int col = ct * 16 + l15;
            float h = acc[ct][r] + bself[col] + dg * bmsg[col];
            h = fmaxf(h, 0.f);
            v[ct] = h;
            s1 += h;
        }
        if (do_ln) {
#pragma unroll
            for (int m = 1; m < 16; m <<= 1) s1 += __shfl_xor(s1, m, 64);
            float mu = s1 * (1.0f / 128.0f);
            float s2 = 0.f;
#pragma unroll
            for (int ct = 0; ct < 8; ct++) { float d = v[ct] - mu; s2 += d * d; }
#pragma unroll
            for (int m = 1; m < 16; m <<= 1) s2 += __shfl_xor(s2, m, 64);
            float rs = rsqrtf(s2 * (1.0f / 128.0f) + LN_EPS);
#pragma unroll
            for (int ct = 0; ct < 8; ct++) {
                int col = ct * 16 + l15;
                v[ct] = lng[col] * (v[ct] - mu) * rs + lnb[col];
            }
        }
        if (do_pool) {
            if (fastp) {
#pragma unroll
                for (int ct = 0; ct < 8; ct++) racc[ct] += v[ct];
            } else if (valid) {
                int g = batch[grow];
#pragma unroll
                for (int ct = 0; ct < 8; ct++)
                    atomicAdd(&gsum[g * DIM + ct * 16 + l15], v[ct]);
            }
        } else if (valid) {
            // chunk-major store: col = ct*16+l15 -> chunk ct>>1, elem (ct&1)*16+l15
#pragma unroll
            for (int ct = 0; ct < 8; ct++) {
                __hip_bfloat16 hv = __float2bfloat16(v[ct]);
                __builtin_nontemporal_store(*(unsigned short*)&hv,
                    (unsigned short*)Xout +
                        ((size_t)(ct >> 1) * ROWS1 + grow) * CW + (ct & 1) * 16 + l15);
            }
        }
    }
    if (do_pool && fastp) {
#pragma unroll
        for (int ct = 0; ct < 8; ct++) {
            racc[ct] += __shfl_xor(racc[ct], 16, 64);
            racc[ct] += __shfl_xor(racc[ct], 32, 64);
        }
        if (q == 0) {
#pragma unroll
            for (int ct = 0; ct < 8; ct++)
                atomicAdd(&gsum[gw * DIM + ct * 16 + l15], racc[ct]);
        }
    }
}

// ---- head: mean + MLP + log_softmax ----------------------------------------

__global__ __launch_bounds__(128) void head_kernel(
    const float* __restrict__ gsum, const int* __restrict__ batch,
    const float* __restrict__ W1, const float* __restrict__ b1,
    const float* __restrict__ W2, const float* __restrict__ b2,
    float* __restrict__ out) {
    __shared__ float p[128];
    __shared__ float hh[128];
    int g = blockIdx.x;
    int j = threadIdx.x;
    int lo = lower_bound_i(batch, N_NODES, g);
    int hi = lower_bound_i(batch, N_NODES, g + 1);
    float cnt = fmaxf((float)(hi - lo), 1.0f);
    p[j] = gsum[g * DIM + j] / cnt;
    __syncthreads();
    float s = b1[j];
    for (int k = 0; k < DIM; k++) s += p[k] * W1[k * DIM + j];
    hh[j] = s;
    __syncthreads();
    if (j < CLS) {
        float l = b2[j];
        for (int k = 0; k < DIM; k++) l += hh[k] * W2[k * CLS + j];
        float mx = l;
#pragma unroll
        for (int m = 16; m >= 1; m >>= 1) mx = fmaxf(mx, __shfl_xor(mx, m, 64));
        float ex = expf(l - mx);
        float se = ex;
#pragma unroll
        for (int m = 16; m >= 1; m >>= 1) se += __shfl_xor(se, m, 64);
        out[g * CLS + j] = l - mx - logf(se);
    }
}

// ---- launch ----------------------------------------------------------------

extern "C" void kernel_launch(void* const* d_in, const int* in_sizes, int n_in,
                              void* d_out, int out_size, void* d_ws, size_t ws_size,
                              hipStream_t stream) {
    (void)in_sizes; (void)n_in; (void)out_size; (void)ws_size;
    const float* x     = (const float*)d_in[0];
    const float* Wself = (const float*)d_in[1];
    const float* bself = (const float*)d_in[2];
    const float* Wmsg  = (const float*)d_in[3];
    const float* bmsg  = (const float*)d_in[4];
    const float* lng   = (const float*)d_in[5];
    const float* lnb   = (const float*)d_in[6];
    const float* W1    = (const float*)d_in[7];
    const float* b1    = (const float*)d_in[8];
    const float* W2    = (const float*)d_in[9];
    const float* b2    = (const float*)d_in[10];
    const int*   ei    = (const int*)d_in[11];
    const int*   batch = (const int*)d_in[12];
    const int* esrc = ei;
    const int* edst = ei + N_EDGES;

    char* w = (char*)d_ws;
    size_t o = 0;
    auto alloc = [&](size_t bytes) { void* p = w + o; o += (bytes + 255) & ~(size_t)255; return p; };
    const size_t XSZ = (size_t)CHK * ROWS1 * CW * 2;  // 12.8 MB chunk-major
    __hip_bfloat16* XbIn = (__hip_bfloat16*)alloc(XSZ);
    __hip_bfloat16* Xb0  = (__hip_bfloat16*)alloc(XSZ);
    __hip_bfloat16* Xb1  = (__hip_bfloat16*)alloc(XSZ);
    __hip_bfloat16* Sg   = (__hip_bfloat16*)alloc(XSZ);
    __hip_bfloat16* WTf  = (__hip_bfloat16*)alloc((size_t)3 * 32768 * 2);
    int*   counts = (int*)alloc((size_t)N_NODES * 4);
    int*   offs   = (int*)alloc((size_t)NPAD * 4);
    int*   offe   = (int*)alloc((size_t)NPAD * 4);
    int*   ecur   = (int*)alloc((size_t)NBLK * 4);
    int*   ebuf   = (int*)alloc((size_t)NBLK * EB_STRIDE * 4);
    unsigned short* csr = (unsigned short*)alloc((size_t)NBLK * LCAP * 2);
    float* gsum   = (float*)alloc((size_t)NGRAPH * DIM * 4);

    // fused prep: chunk-major bf16 convert + WTf shuffle + zero scratch/pads
    prep_kernel<<<(N_NODES * DIM / 2 + 255) / 256, 256, 0, stream>>>(
        x, Wself, Wmsg, XbIn, WTf, ecur, gsum, offs, offe, XbIn, Xb0, Xb1, Sg);

    // CSR build: bucket -> fused(hist+scan+build), fixed per-bucket stride
    bucket_kernel<<<ABLK, 1024, 0, stream>>>(esrc, edst, ecur, ebuf);
    csr_fused_kernel<<<NBLK, 1024, 0, stream>>>(ebuf, ecur, counts, offs, offe, csr);

    const __hip_bfloat16* XbCur = XbIn;
    __hip_bfloat16* bbufs[3] = {Xb0, Xb1, Xb0};
    for (int i = 0; i < 3; i++) {
        agg_kernel<<<8 * SLOTH, 1024, 0, stream>>>(XbCur, offs, offe, csr, Sg);
        layer_mfma_kernel<<<(N_NODES + 63) / 64, 256, 0, stream>>>(
            XbCur, Sg, WTf + (size_t)i * 32768,
            bself + i * DIM, bmsg + i * DIM, counts,
            (i < 2) ? lng + i * DIM : lng, (i < 2) ? lnb + i * DIM : lnb,
            batch, gsum,
            bbufs[i], (i < 2) ? 1 : 0, (i == 2) ? 1 : 0);
        XbCur = bbufs[i];
    }

    head_kernel<<<NGRAPH, 128, 0, stream>>>(gsum, batch, W1, b1, W2, b2, (float*)d_out);
}

// Round 8
// 278.385 us; speedup vs baseline: 1.2886x; 1.0119x over previous
//
#include <hip/hip_runtime.h>
#include <hip/hip_bf16.h>
#include <math.h>

#define N_NODES 50000
#define N_EDGES 800000
#define DIM 128
#define CLS 32
#define NGRAPH 64
#define LN_EPS 1e-5f
#define NBLK 196                         // dst-buckets of 256 nodes
#define ABLK 256                         // phase-A blocks (1 per CU)
#define EPB (N_EDGES / ABLK)             // 3125 edges per phase-A block
#define EB_STRIDE 7168                   // per-bucket ebuf capacity
#define LCAP 8192                        // per-bucket CSR capacity (fixed stride)
#define ROWS1 (N_NODES + 1)              // 50001 (incl zero pad row)
#define CHK 4                            // feature chunks
#define CW 32                            // features per chunk (64 B rows)
#define NPW 4                            // nodes per agg wave (4 chains in flight)
#define NPAD 50048                       // padded node-meta entries
#define AGG_WPB 4                        // agg waves per block (256 threads)
#define AGG_NPB (AGG_WPB * NPW)          // 16 nodes per agg block
#define AGG_NCB ((N_NODES + AGG_NPB - 1) / AGG_NPB)  // 3125 node-blocks/chunk
#define AGG_SLOT ((AGG_NCB + 1) / 2)     // 1563 node-blocks per XCD slot-half

typedef __attribute__((ext_vector_type(8))) short bf16x8;
typedef __attribute__((ext_vector_type(4))) float f32x4;
typedef __attribute__((ext_vector_type(2))) unsigned int u32x2;

static __device__ __forceinline__ int lower_bound_i(const int* a, int n, int key) {
    int lo = 0, hi = n;
    while (lo < hi) { int mid = (lo + hi) >> 1; if (a[mid] < key) lo = mid + 1; else hi = mid; }
    return lo;
}

// accumulate 4 bf16 (one u32x2) into 4 f32
static __device__ __forceinline__ void acc4(float* ac, u32x2 v) {
    union { unsigned int b; float f; } lo0, hi0, lo1, hi1;
    lo0.b = v.x << 16;
    hi0.b = v.x & 0xffff0000u;
    lo1.b = v.y << 16;
    hi1.b = v.y & 0xffff0000u;
    ac[0] += lo0.f;
    ac[1] += hi0.f;
    ac[2] += lo1.f;
    ac[3] += hi1.f;
}

// ---- fused prep: chunk-major bf16 convert + weight fragment shuffle --------
// Node buffers chunk-major [CHK][ROWS1][CW]; chunk c = features c*32..c*32+31.
// WTf per layer: [half(2)][ct(8)][ks(4)][lane(64)][e(8)] -- half 0 = Wself,
// half 1 = Wmsg; n = ct*16+(lane&15), k = half*128 + ks*32 + (lane>>4)*8 + e.
// Each half is one contiguous 32 KB slab (block-stageable with one memcpy).

__global__ __launch_bounds__(256) void prep_kernel(
    const float* __restrict__ x, const float* __restrict__ Wself,
    const float* __restrict__ Wmsg, __hip_bfloat16* __restrict__ XbIn,
    __hip_bfloat16* __restrict__ WTf,
    int* __restrict__ ecur, float* __restrict__ gsum,
    int* __restrict__ off, int* __restrict__ offe,
    __hip_bfloat16* __restrict__ padA, __hip_bfloat16* __restrict__ padB,
    __hip_bfloat16* __restrict__ padC, __hip_bfloat16* __restrict__ padD) {
    int i = blockIdx.x * 256 + threadIdx.x;  // grid covers N_NODES*DIM/2 = 3.2M
    if (i < N_NODES * DIM / 2) {
        float2 v = ((const float2*)x)[i];
        int n = i >> 6, kk = i & 63;          // kk indexes feature pairs
        int c = kk >> 4;
        __hip_bfloat162 hv = __float22bfloat162_rn(v);
        __builtin_nontemporal_store(*(unsigned int*)&hv,
            (unsigned int*)XbIn + ((size_t)c * ROWS1 + n) * 16 + (kk & 15));
    }
    if (i < 3 * 32768) {
        int l = i >> 15;
        int rem = i & 32767;
        int half = rem >> 14;
        int rem2 = rem & 16383;
        int ct = rem2 >> 11;
        int ks = (rem2 >> 9) & 3;
        int lane = (rem2 >> 3) & 63;
        int e = rem2 & 7;
        int q = lane >> 4, l15 = lane & 15;
        int n = ct * 16 + l15;
        int k = half * 128 + ks * 32 + q * 8 + e;
        float v = (k < 128) ? Wself[l * 16384 + k * 128 + n]
                            : Wmsg[l * 16384 + (k - 128) * 128 + n];
        WTf[i] = __float2bfloat16(v);
    }
    if (i < NBLK) ecur[i] = i * EB_STRIDE;
    if (i < NGRAPH * DIM) gsum[i] = 0.f;
    if (i >= N_NODES && i < NPAD) { off[i] = 0; offe[i] = 0; }  // pad node meta
    if (i < 4 * CHK * CW) {  // zero pad row (n = N_NODES) in every chunk
        __hip_bfloat16* bufs[4] = {padA, padB, padC, padD};
        int buf = i >> 7, c = (i >> 5) & 3, e = i & 31;
        bufs[buf][((size_t)c * ROWS1 + N_NODES) * CW + e] = __float2bfloat16(0.f);
    }
}

// ---- phase A: bucket edges by dst>>8, line-exclusive reservations ----------

__global__ __launch_bounds__(1024) void bucket_kernel(
    const int* __restrict__ esrc, const int* __restrict__ edst,
    int* __restrict__ ecur, int* __restrict__ ebuf) {
    __shared__ int bc4[4][NBLK];
    __shared__ int bc[NBLK], bres[NBLK], bcnt[NBLK];
    const int t = threadIdx.x;
    const int e0 = blockIdx.x * EPB;
    for (int i = t; i < 4 * NBLK; i += 1024) ((int*)bc4)[i] = 0;
    __syncthreads();
    int dr[4], sr[4];
#pragma unroll
    for (int it = 0; it < 4; it++) {
        int i = t + it * 1024;
        if (i < EPB) { dr[it] = edst[e0 + i]; sr[it] = esrc[e0 + i]; }
        else { dr[it] = -1; sr[it] = 0; }
    }
    const int cpy = (t >> 6) & 3;
#pragma unroll
    for (int it = 0; it < 4; it++)
        if (dr[it] >= 0) atomicAdd(&bc4[cpy][dr[it] >> 8], 1);
    __syncthreads();
    if (t < NBLK) {
        int c = bc4[0][t] + bc4[1][t] + bc4[2][t] + bc4[3][t];
        int r = (c + 7) & ~7;                   // pad to multiple of 8
        int res = atomicAdd(&ecur[t], r);       // one global atomic per (block,bucket)
        bres[t] = res;
        bcnt[t] = c;
        bc[t] = res;
    }
    __syncthreads();
#pragma unroll
    for (int it = 0; it < 4; it++)
        if (dr[it] >= 0) {
            int d = dr[it];
            int pos = atomicAdd(&bc[d >> 8], 1);
            ebuf[pos] = ((d & 255) << 16) | sr[it];  // src < 50000 < 2^16
        }
    __syncthreads();
    if (t < NBLK) {
        int c = bcnt[t], r = (c + 7) & ~7, base = bres[t];
        for (int j = c; j < r; j++) ebuf[base + j] = -1;  // sentinels
    }
}

// ---- phase B (fused): per-bucket hist + scan + CSR build in LDS ------------
// csr stored as ushort (src < 2^16); pad entries point at zero row N_NODES.
// Also writes offe[] = off + padded count (agg consumes off/offe via s_load).

__global__ __launch_bounds__(1024) void csr_fused_kernel(
    const int* __restrict__ ebuf, const int* __restrict__ ecur,
    int* __restrict__ counts, int* __restrict__ off, int* __restrict__ offe,
    unsigned short* __restrict__ csr) {
    __shared__ int ncnt[256];
    __shared__ int ssc[256];
    __shared__ int cur[256];
    __shared__ unsigned short lcsr[LCAP];
    const int b = blockIdx.x, t = threadIdx.x;
    const int used = ecur[b] - b * EB_STRIDE;
    const int* eb = ebuf + b * EB_STRIDE;
    for (int i = t; i < LCAP / 2; i += 1024)
        ((unsigned int*)lcsr)[i] = 0xC350C350u;  // 50000 | 50000<<16
    if (t < 256) ncnt[t] = 0;
    __syncthreads();
    for (int i = t; i < used; i += 1024) {
        int p = eb[i];
        if (p != -1) atomicAdd(&ncnt[p >> 16], 1);
    }
    __syncthreads();
    int myc = 0, mypad = 0;
    const int gi = b * 256 + t;
    if (t < 256) {
        myc = (gi < N_NODES) ? ncnt[t] : 0;
        mypad = (myc + 7) & ~7;
        ssc[t] = mypad;
    }
    __syncthreads();
    for (int o = 1; o < 256; o <<= 1) {
        int v = 0;
        if (t < 256 && t >= o) v = ssc[t - o];
        __syncthreads();
        if (t < 256) ssc[t] += v;
        __syncthreads();
    }
    if (t < 256) {
        int eoff = ssc[t] - mypad;
        cur[t] = eoff;
        if (gi < N_NODES) {
            off[gi] = b * LCAP + eoff;
            offe[gi] = b * LCAP + eoff + mypad;
            counts[gi] = myc;
        }
    }
    __syncthreads();
    for (int i = t; i < used; i += 1024) {
        int p = eb[i];
        if (p != -1) {
            int pos = atomicAdd(&cur[p >> 16], 1);
            lcsr[pos] = (unsigned short)(p & 0xFFFF);
        }
    }
    __syncthreads();
    const int total = ssc[255];                 // multiple of 8
    int4* dst4 = (int4*)(csr + (size_t)b * LCAP);
    const int4* src4 = (const int4*)lcsr;
    for (int i = t; i < (total >> 3); i += 1024) dst4[i] = src4[i];
}

// ---- agg v8: XCD-pinned, 32-edge rounds, csr software pipeline -------------
// 256-thread blocks (finer tail packing). Per round per node: one uint2 csr
// load per 8-lane group (4 edges) -> 4 gathers/node = 16 gathers in flight
// per wave. The NEXT round's csr load issues before the acc waits on this
// round's gathers, so the csr->gather chain latencies overlap. Tails:
// one predicated 16-edge round + one 8-edge round (remaining is 0/8/16/24).

__global__ __launch_bounds__(256) void agg_kernel(
    const __hip_bfloat16* __restrict__ Xg, const int* __restrict__ off,
    const int* __restrict__ offe, const unsigned short* __restrict__ csr,
    __hip_bfloat16* __restrict__ Sg) {
    const int b = blockIdx.x;
    const int slot = b & 7;
    const int chunk = slot & 3;
    const int half = slot >> 2;
    const int nbidx = (b >> 3) * 2 + half;      // [0, 2*AGG_SLOT)
    const int w = __builtin_amdgcn_readfirstlane(threadIdx.x >> 6);
    const int lane = threadIdx.x & 63;
    const int l8 = lane & 7, g8 = lane >> 3;
    const char* X = (const char*)(Xg + (size_t)chunk * ROWS1 * CW);
    const char* C = (const char*)csr;
    const int nbase = nbidx * AGG_NPB + w * NPW;  // SGPR; < NPAD (pads: off==offe==0)
    const int loff = l8 * 8;                    // byte offset within 64 B row
    const int c2off = g8 * 8;                   // uint2 csr offset (4 edges/group)
    const int c1off = g8 * 4;                   // uint csr offset (2 edges/group)

    int bj[NPW], ej[NPW];
    float ac[NPW][4];
#pragma unroll
    for (int j = 0; j < NPW; j++) {
        int n = nbase + j;
        bj[j] = off[n];
        ej[j] = offe[n];
        ac[j][0] = ac[j][1] = ac[j][2] = ac[j][3] = 0.f;
    }

    // ---- 32-edge rounds, pipelined csr ----
    u32x2 u[NPW];
    int act = 0;
#pragma unroll
    for (int j = 0; j < NPW; j++)
        if (bj[j] + 32 <= ej[j]) {
            act |= (1 << j);
            u[j] = *(const u32x2*)(C + bj[j] * 2 + c2off);
        }
    while (act) {
        u32x2 v0[NPW], v1[NPW], v2[NPW], v3[NPW];
#pragma unroll
        for (int j = 0; j < NPW; j++)
            if (act & (1 << j)) {
                int s0 = u[j].x & 0xffff, s1 = u[j].x >> 16;
                int s2 = u[j].y & 0xffff, s3 = u[j].y >> 16;
                v0[j] = *(const u32x2*)(X + ((s0 << 6) | loff));
                v1[j] = *(const u32x2*)(X + ((s1 << 6) | loff));
                v2[j] = *(const u32x2*)(X + ((s2 << 6) | loff));
                v3[j] = *(const u32x2*)(X + ((s3 << 6) | loff));
            }
        int nact = 0;
        u32x2 un[NPW];
#pragma unroll
        for (int j = 0; j < NPW; j++)
            if (act & (1 << j)) {
                bj[j] += 32;
                if (bj[j] + 32 <= ej[j]) {
                    nact |= (1 << j);
                    un[j] = *(const u32x2*)(C + bj[j] * 2 + c2off);  // issued pre-acc
                }
            }
#pragma unroll
        for (int j = 0; j < NPW; j++)
            if (act & (1 << j)) {
                acc4(ac[j], v0[j]);
                acc4(ac[j], v1[j]);
                acc4(ac[j], v2[j]);
                acc4(ac[j], v3[j]);
            }
#pragma unroll
        for (int j = 0; j < NPW; j++) u[j] = un[j];
        act = nact;
    }
    // ---- 16-edge tail round (remaining 0/8/16/24) ----
    {
        unsigned int ut[NPW];
        int tact = 0;
#pragma unroll
        for (int j = 0; j < NPW; j++)
            if (bj[j] + 16 <= ej[j]) {
                tact |= (1 << j);
                ut[j] = *(const unsigned int*)(C + bj[j] * 2 + c1off);
            }
#pragma unroll
        for (int j = 0; j < NPW; j++)
            if (tact & (1 << j)) {
                int s0 = ut[j] & 0xffff, s1 = ut[j] >> 16;
                u32x2 a = *(const u32x2*)(X + ((s0 << 6) | loff));
                u32x2 c = *(const u32x2*)(X + ((s1 << 6) | loff));
                acc4(ac[j], a);
                acc4(ac[j], c);
                bj[j] += 16;
            }
    }
    // ---- 8-edge tail round ----
    {
        unsigned int ut[NPW];
        int tact = 0;
#pragma unroll
        for (int j = 0; j < NPW; j++)
            if (bj[j] < ej[j]) {
                tact |= (1 << j);
                ut[j] = csr[bj[j] + g8];
            }
#pragma unroll
        for (int j = 0; j < NPW; j++)
            if (tact & (1 << j)) {
                u32x2 v = *(const u32x2*)(X + (((int)ut[j] << 6) | loff));
                acc4(ac[j], v);
            }
    }
    // reduce across the 8 lane-groups (lane bits 3,4,5)
#pragma unroll
    for (int j = 0; j < NPW; j++)
#pragma unroll
        for (int k = 0; k < 4; k++) {
            ac[j][k] += __shfl_xor(ac[j][k], 8, 64);
            ac[j][k] += __shfl_xor(ac[j][k], 16, 64);
            ac[j][k] += __shfl_xor(ac[j][k], 32, 64);
        }
    if (lane < 8) {
#pragma unroll
        for (int j = 0; j < NPW; j++) {
            int n = nbase + j;
            if (n < N_NODES) {
                union { u32x2 u; __hip_bfloat162 h[2]; } pk;
                pk.h[0] = __float22bfloat162_rn(make_float2(ac[j][0], ac[j][1]));
                pk.h[1] = __float22bfloat162_rn(make_float2(ac[j][2], ac[j][3]));
                __builtin_nontemporal_store(pk.u,
                    (u32x2*)(Sg + ((size_t)chunk * ROWS1 + n) * CW + lane * 4));
            }
        }
    }
}

// ---- layer: MFMA H = [Xg|Sg] @ W^T with block-staged LDS weights -----------
// (unchanged from R7: layers dropped below the fill threshold)

__global__ __launch_bounds__(256) void layer_mfma_kernel(
    const __hip_bfloat16* __restrict__ Xg, const __hip_bfloat16* __restrict__ Sg,
    const __hip_bfloat16* __restrict__ WTf,  // [2][8][4][64][8] this layer
    const float* __restrict__ bself, const float* __restrict__ bmsg,
    const int* __restrict__ counts,
    const float* __restrict__ lng, const float* __restrict__ lnb,
    const int* __restrict__ batch, float* __restrict__ gsum,
    __hip_bfloat16* __restrict__ Xout, int do_ln, int do_pool) {
    __shared__ __hip_bfloat16 wlds[16384];     // 32 KB: one half of WTf
    const int tid = threadIdx.x;
    const int w = tid >> 6, lane = tid & 63;
    const int l15 = lane & 15, q = lane >> 4;
    const int growbase = blockIdx.x * 64 + w * 16;
    const int row = growbase + l15;
    const int rowc = min(row, N_NODES);  // pad row N_NODES is all zeros

    f32x4 acc[8];
#pragma unroll
    for (int ct = 0; ct < 8; ct++) acc[ct] = (f32x4){0.f, 0.f, 0.f, 0.f};

    // stage Wself half (32 KB, contiguous, coalesced, conflict-free)
    {
        const uint4* src = (const uint4*)WTf;
        uint4* dst = (uint4*)wlds;
#pragma unroll
        for (int i = 0; i < 8; i++) dst[tid + i * 256] = src[tid + i * 256];
    }
    __syncthreads();
#pragma unroll
    for (int ks = 0; ks < 4; ks++) {
        bf16x8 afrag = *(const bf16x8*)(Xg + ((size_t)ks * ROWS1 + rowc) * CW + q * 8);
#pragma unroll
        for (int ct = 0; ct < 8; ct++) {
            bf16x8 bfrag = *(const bf16x8*)(&wlds[(((ct * 4 + ks) * 64) + lane) * 8]);
            acc[ct] = __builtin_amdgcn_mfma_f32_16x16x32_bf16(afrag, bfrag, acc[ct], 0, 0, 0);
        }
    }
    __syncthreads();
    // stage Wmsg half
    {
        const uint4* src = (const uint4*)(WTf + 16384);
        uint4* dst = (uint4*)wlds;
#pragma unroll
        for (int i = 0; i < 8; i++) dst[tid + i * 256] = src[tid + i * 256];
    }
    __syncthreads();
#pragma unroll
    for (int ks = 0; ks < 4; ks++) {
        bf16x8 afrag = *(const bf16x8*)(Sg + ((size_t)ks * ROWS1 + rowc) * CW + q * 8);
#pragma unroll
        for (int ct = 0; ct < 8; ct++) {
            bf16x8 bfrag = *(const bf16x8*)(&wlds[(((ct * 4 + ks) * 64) + lane) * 8]);
            acc[ct] = __builtin_amdgcn_mfma_f32_16x16x32_bf16(afrag, bfrag, acc[ct], 0, 0, 0);
        }
    }

    // ---- epilogue: lane holds rows (q*4+r), cols (ct*16+l15) ----
    float racc[8];
#pragma unroll
    for (int ct = 0; ct < 8; ct++) racc[ct] = 0.f;
    int gw = 0;
    bool fastp = false;
    if (do_pool) {
        int first = (growbase < N_NODES) ? growbase : (N_NODES - 1);
        gw = batch[first];
        int lastrow = growbase + 15;
        fastp = (growbase < N_NODES) && (lastrow < N_NODES) && (batch[lastrow] == gw);
    }
#pragma unroll
    for (int r = 0; r < 4; r++) {
        int grow = growbase + q * 4 + r;
        bool valid = grow < N_NODES;
        float dg = valid ? (float)counts[grow] : 0.f;
        float v[8];
        float s1 = 0.f;
#pragma unroll
        for (int ct = 0; ct < 8; ct++) {
            int col = ct * 16 + l15;
            float h = acc[ct][r] + bself[col] + dg * bmsg[col];
            h = fmaxf(h, 0.f);
            v[ct] = h;
            s1 += h;
        }
        if (do_ln) {
#pragma unroll
            for (int m = 1; m < 16; m <<= 1) s1 += __shfl_xor(s1, m, 64);
            float mu = s1 * (1.0f / 128.0f);
            float s2 = 0.f;
#pragma unroll
            for (int ct = 0; ct < 8; ct++) { float d = v[ct] - mu; s2 += d * d; }
#pragma unroll
            for (int m = 1; m < 16; m <<= 1) s2 += __shfl_xor(s2, m, 64);
            float rs = rsqrtf(s2 * (1.0f / 128.0f) + LN_EPS);
#pragma unroll
            for (int ct = 0; ct < 8; ct++) {
                int col = ct * 16 + l15;
                v[ct] = lng[col] * (v[ct] - mu) * rs + lnb[col];
            }
        }
        if (do_pool) {
            if (fastp) {
#pragma unroll
                for (int ct = 0; ct < 8; ct++) racc[ct] += v[ct];
            } else if (valid) {
                int g = batch[grow];
#pragma unroll
                for (int ct = 0; ct < 8; ct++)
                    atomicAdd(&gsum[g * DIM + ct * 16 + l15], v[ct]);
            }
        } else if (valid) {
            // chunk-major store: col = ct*16+l15 -> chunk ct>>1, elem (ct&1)*16+l15
#pragma unroll
            for (int ct = 0; ct < 8; ct++) {
                __hip_bfloat16 hv = __float2bfloat16(v[ct]);
                __builtin_nontemporal_store(*(unsigned short*)&hv,
                    (unsigned short*)Xout +
                        ((size_t)(ct >> 1) * ROWS1 + grow) * CW + (ct & 1) * 16 + l15);
            }
        }
    }
    if (do_pool && fastp) {
#pragma unroll
        for (int ct = 0; ct < 8; ct++) {
            racc[ct] += __shfl_xor(racc[ct], 16, 64);
            racc[ct] += __shfl_xor(racc[ct], 32, 64);
        }
        if (q == 0) {
#pragma unroll
            for (int ct = 0; ct < 8; ct++)
                atomicAdd(&gsum[gw * DIM + ct * 16 + l15], racc[ct]);
        }
    }
}

// ---- head: mean + MLP + log_softmax ----------------------------------------

__global__ __launch_bounds__(128) void head_kernel(
    const float* __restrict__ gsum, const int* __restrict__ batch,
    const float* __restrict__ W1, const float* __restrict__ b1,
    const float* __restrict__ W2, const float* __restrict__ b2,
    float* __restrict__ out) {
    __shared__ float p[128];
    __shared__ float hh[128];
    int g = blockIdx.x;
    int j = threadIdx.x;
    int lo = lower_bound_i(batch, N_NODES, g);
    int hi = lower_bound_i(batch, N_NODES, g + 1);
    float cnt = fmaxf((float)(hi - lo), 1.0f);
    p[j] = gsum[g * DIM + j] / cnt;
    __syncthreads();
    float s = b1[j];
    for (int k = 0; k < DIM; k++) s += p[k] * W1[k * DIM + j];
    hh[j] = s;
    __syncthreads();
    if (j < CLS) {
        float l = b2[j];
        for (int k = 0; k < DIM; k++) l += hh[k] * W2[k * CLS + j];
        float mx = l;
#pragma unroll
        for (int m = 16; m >= 1; m >>= 1) mx = fmaxf(mx, __shfl_xor(mx, m, 64));
        float ex = expf(l - mx);
        float se = ex;
#pragma unroll
        for (int m = 16; m >= 1; m >>= 1) se += __shfl_xor(se, m, 64);
        out[g * CLS + j] = l - mx - logf(se);
    }
}

// ---- launch ----------------------------------------------------------------

extern "C" void kernel_launch(void* const* d_in, const int* in_sizes, int n_in,
                              void* d_out, int out_size, void* d_ws, size_t ws_size,
                              hipStream_t stream) {
    (void)in_sizes; (void)n_in; (void)out_size; (void)ws_size;
    const float* x     = (const float*)d_in[0];
    const float* Wself = (const float*)d_in[1];
    const float* bself = (const float*)d_in[2];
    const float* Wmsg  = (const float*)d_in[3];
    const float* bmsg  = (const float*)d_in[4];
    const float* lng   = (const float*)d_in[5];
    const float* lnb   = (const float*)d_in[6];
    const float* W1    = (const float*)d_in[7];
    const float* b1    = (const float*)d_in[8];
    const float* W2    = (const float*)d_in[9];
    const float* b2    = (const float*)d_in[10];
    const int*   ei    = (const int*)d_in[11];
    const int*   batch = (const int*)d_in[12];
    const int* esrc = ei;
    const int* edst = ei + N_EDGES;

    char* w = (char*)d_ws;
    size_t o = 0;
    auto alloc = [&](size_t bytes) { void* p = w + o; o += (bytes + 255) & ~(size_t)255; return p; };
    const size_t XSZ = (size_t)CHK * ROWS1 * CW * 2;  // 12.8 MB chunk-major
    __hip_bfloat16* XbIn = (__hip_bfloat16*)alloc(XSZ);
    __hip_bfloat16* Xb0  = (__hip_bfloat16*)alloc(XSZ);
    __hip_bfloat16* Xb1  = (__hip_bfloat16*)alloc(XSZ);
    __hip_bfloat16* Sg   = (__hip_bfloat16*)alloc(XSZ);
    __hip_bfloat16* WTf  = (__hip_bfloat16*)alloc((size_t)3 * 32768 * 2);
    int*   counts = (int*)alloc((size_t)N_NODES * 4);
    int*   offs   = (int*)alloc((size_t)NPAD * 4);
    int*   offe   = (int*)alloc((size_t)NPAD * 4);
    int*   ecur   = (int*)alloc((size_t)NBLK * 4);
    int*   ebuf   = (int*)alloc((size_t)NBLK * EB_STRIDE * 4);
    unsigned short* csr = (unsigned short*)alloc((size_t)NBLK * LCAP * 2);
    float* gsum   = (float*)alloc((size_t)NGRAPH * DIM * 4);

    // fused prep: chunk-major bf16 convert + WTf shuffle + zero scratch/pads
    prep_kernel<<<(N_NODES * DIM / 2 + 255) / 256, 256, 0, stream>>>(
        x, Wself, Wmsg, XbIn, WTf, ecur, gsum, offs, offe, XbIn, Xb0, Xb1, Sg);

    // CSR build: bucket -> fused(hist+scan+build), fixed per-bucket stride
    bucket_kernel<<<ABLK, 1024, 0, stream>>>(esrc, edst, ecur, ebuf);
    csr_fused_kernel<<<NBLK, 1024, 0, stream>>>(ebuf, ecur, counts, offs, offe, csr);

    const __hip_bfloat16* XbCur = XbIn;
    __hip_bfloat16* bbufs[3] = {Xb0, Xb1, Xb0};
    for (int i = 0; i < 3; i++) {
        agg_kernel<<<8 * AGG_SLOT, 256, 0, stream>>>(XbCur, offs, offe, csr, Sg);
        layer_mfma_kernel<<<(N_NODES + 63) / 64, 256, 0, stream>>>(
            XbCur, Sg, WTf + (size_t)i * 32768,
            bself + i * DIM, bmsg + i * DIM, counts,
            (i < 2) ? lng + i * DIM : lng, (i < 2) ? lnb + i * DIM : lnb,
            batch, gsum,
            bbufs[i], (i < 2) ? 1 : 0, (i == 2) ? 1 : 0);
        XbCur = bbufs[i];
    }

    head_kernel<<<NGRAPH, 128, 0, stream>>>(gsum, batch, W1, b1, W2, b2, (float*)d_out);
}